// Round 8
// baseline (408.778 us; speedup 1.0000x reference)
//
#include <hip/hip_runtime.h>
#include <hip/hip_bf16.h>
#include <cstdio>

#define TPB 256
#define B_ 4
#define H_ 128
#define W_ 128
#define D_ 768
#define FW 65
#define BH_ 512                  // B_*H_
#define THRESH_ 0.01f
#define NEG_TWO_PI_OVER_128 (-0.04908738521234052f)

typedef short bf16x8 __attribute__((ext_vector_type(8)));
typedef float f32x4 __attribute__((ext_vector_type(4)));

// fq (in d_ws): one u32 per (point, channel) = packed (bf16 re, bf16 im)
//   u32 index = ((b*128 + h)*65 + fw)*768 + d     (h natural order everywhere)
// Mixed-radix 128 = 4*4*4*2 DIF; in-place slot s holds digit-reversed bin;
//   drev / drevinv only matter inside the W-axis kernels.

__device__ __forceinline__ unsigned pk(float lo, float hi) {
  __hip_bfloat162 h2 = __float22bfloat162_rn(make_float2(lo, hi));
  return *(unsigned*)&h2;
}
__device__ __forceinline__ float2 upk(unsigned u) {
  return __bfloat1622float2(*(__hip_bfloat162*)&u);
}
__device__ __forceinline__ int drev(int k) {
  return ((k & 3) << 5) | (((k >> 2) & 3) << 3) | (((k >> 4) & 3) << 1) | ((k >> 6) & 1);
}
__device__ __forceinline__ int drevinv(int s) {
  return ((s & 1) << 6) | (((s >> 1) & 3) << 4) | (((s >> 3) & 3) << 2) | ((s >> 5) & 3);
}

// register radix-4 DIF butterfly. FWD: e^-i; !FWD: e^+i (pass negated twi).
template <bool FWD>
__device__ __forceinline__ void bf4reg(float& x0r, float& x0i, float& x1r, float& x1i,
                                       float& x2r, float& x2i, float& x3r, float& x3i,
                                       float c1, float s1, float c2, float s2, float c3, float s3) {
  const float v0r = x0r + x2r, v0i = x0i + x2i, v2r = x0r - x2r, v2i = x0i - x2i;
  const float v1r = x1r + x3r, v1i = x1i + x3i, v3r = x1r - x3r, v3i = x1i - x3i;
  float u1r, u1i, u3r, u3i;
  if (FWD) { u1r = v2r + v3i; u1i = v2i - v3r; u3r = v2r - v3i; u3i = v2i + v3r; }
  else     { u1r = v2r - v3i; u1i = v2i + v3r; u3r = v2r + v3i; u3i = v2i - v3r; }
  const float u2r = v0r - v1r, u2i = v0i - v1i;
  x0r = v0r + v1r;            x0i = v0i + v1i;
  x1r = u1r * c1 - u1i * s1;  x1i = u1r * s1 + u1i * c1;
  x2r = u2r * c2 - u2i * s2;  x2i = u2r * s2 + u2i * c2;
  x3r = u3r * c3 - u3i * s3;  x3i = u3r * s3 + u3i * c3;
}

// register inverse radix-4 butterfly (DIT: conj-twiddle inputs, e^+i DFT4)
__device__ __forceinline__ void ibf4r(float& x0r, float& x0i, float& x1r, float& x1i,
                                      float& x2r, float& x2i, float& x3r, float& x3i,
                                      float c1, float s1, float c2, float s2, float c3, float s3) {
  const float t0r = x0r, t0i = x0i;
  const float t1r = x1r * c1 + x1i * s1, t1i = x1i * c1 - x1r * s1;
  const float t2r = x2r * c2 + x2i * s2, t2i = x2i * c2 - x2r * s2;
  const float t3r = x3r * c3 + x3i * s3, t3i = x3i * c3 - x3r * s3;
  const float w0r = t0r + t2r, w0i = t0i + t2i, w2r = t0r - t2r, w2i = t0i - t2i;
  const float w1r = t1r + t3r, w1i = t1i + t3i, w3r = t1r - t3r, w3i = t1i - t3i;
  x0r = w0r + w1r; x0i = w0i + w1i;
  x1r = w2r - w3i; x1i = w2i + w3r;
  x2r = w0r - w1r; x2i = w0i - w1i;
  x3r = w2r + w3i; x3i = w2i - w3r;
}

#define TW_INIT() do { if (t < 128) { float s_, c_; \
    __sincosf(NEG_TWO_PI_OVER_128 * (float)t, &s_, &c_); twr[t] = c_; twi[t] = s_; } } while (0)

// ---------------------------------------------------------------------------
// K0: pack complex weights into bf16 B-fragment order (block form Wc).
// ---------------------------------------------------------------------------
__global__ __launch_bounds__(TPB) void k_wpack(const float* __restrict__ w1r,
                                               const float* __restrict__ w1i,
                                               const float* __restrict__ w2r,
                                               const float* __restrict__ w2i,
                                               unsigned short* __restrict__ wp) {
  const int tid = blockIdx.x * TPB + threadIdx.x;
  if (tid >= 2 * 36864) return;
  const int L = tid / 36864, rem = tid % 36864;
  const int n = rem / 192, k = rem % 192;
  const int c = k >> 1, s = k & 1, o = n >> 1, t = n & 1;
  const float* wr = L ? w2r : w1r;
  const float* wi = L ? w2i : w1i;
  const float val = (s == 0) ? (t == 0 ? wr[o * 96 + c] : wi[o * 96 + c])
                             : (t == 0 ? -wi[o * 96 + c] : wr[o * 96 + c]);
  __hip_bfloat16 h = __float2bfloat16(val);
  const int idx = ((n * 6 + (k >> 5)) * 4 + ((k >> 3) & 3)) * 8 + (k & 7);
  wp[L * 36864 + idx] = *(unsigned short*)&h;
}

// ---------------------------------------------------------------------------
// K1: forward rFFT over W via real-pair packing, two-phase register fusion.
// grid (512, 12). Writes bf16 fq bins 0..64. (unchanged from round 7)
// ---------------------------------------------------------------------------
__global__ __launch_bounds__(TPB) void k_fwd_w(const float* __restrict__ x,
                                               unsigned* __restrict__ fq) {
  __shared__ float re[4096], im[4096], twr[128], twi[128];
  const int t = threadIdx.x;
  const int bh = blockIdx.x;
  const int d0 = blockIdx.y << 6;
  TW_INIT();
  const int c = t & 31, p = t >> 5;
  const float2* xp = (const float2*)(x + (size_t)bh * 98304 + d0);

  float vr[4][4], vi[4][4];
#pragma unroll
  for (int q = 0; q < 4; ++q)
#pragma unroll
    for (int m = 0; m < 4; ++m) {
      const float2 v = xp[(p + 8 * m + 32 * q) * 384 + c];
      vr[q][m] = v.x; vi[q][m] = v.y;
    }
  __syncthreads();
#pragma unroll
  for (int m = 0; m < 4; ++m) {
    const int np = p + 8 * m;
    bf4reg<true>(vr[0][m], vi[0][m], vr[1][m], vi[1][m], vr[2][m], vi[2][m], vr[3][m], vi[3][m],
                 twr[np], twi[np], twr[2 * np], twi[2 * np], twr[3 * np], twi[3 * np]);
  }
#pragma unroll
  for (int q = 0; q < 4; ++q)
    bf4reg<true>(vr[q][0], vi[q][0], vr[q][1], vi[q][1], vr[q][2], vi[q][2], vr[q][3], vi[q][3],
                 twr[4 * p], twi[4 * p], twr[8 * p], twi[8 * p], twr[12 * p], twi[12 * p]);
#pragma unroll
  for (int q = 0; q < 4; ++q)
#pragma unroll
    for (int m = 0; m < 4; ++m) {
      const int pos = p + 8 * m + 32 * q;
      re[pos * 32 + c] = vr[q][m]; im[pos * 32 + c] = vi[q][m];
    }
  __syncthreads();

#pragma unroll
  for (int half = 0; half < 2; ++half) {
    const int g = 8 * half + p;
    float wr8[8], wi8[8];
#pragma unroll
    for (int j = 0; j < 8; ++j) { wr8[j] = re[(8 * g + j) * 32 + c]; wi8[j] = im[(8 * g + j) * 32 + c]; }
    bf4reg<true>(wr8[0], wi8[0], wr8[2], wi8[2], wr8[4], wi8[4], wr8[6], wi8[6],
                 1.f, 0.f, 1.f, 0.f, 1.f, 0.f);
    bf4reg<true>(wr8[1], wi8[1], wr8[3], wi8[3], wr8[5], wi8[5], wr8[7], wi8[7],
                 twr[16], twi[16], twr[32], twi[32], twr[48], twi[48]);
#pragma unroll
    for (int j = 0; j < 8; j += 2) {
      const float ar = wr8[j], ai = wi8[j], br = wr8[j + 1], bi = wi8[j + 1];
      wr8[j] = ar + br; wi8[j] = ai + bi;
      wr8[j + 1] = ar - br; wi8[j + 1] = ai - bi;
    }
#pragma unroll
    for (int j = 0; j < 8; ++j) {
      re[(8 * g + j) * 32 + c] = wr8[j]; im[(8 * g + j) * 32 + c] = wi8[j];
    }
  }
  __syncthreads();

#pragma unroll
  for (int it = 0; it < 9; ++it) {
    const int idx = it * TPB + t;
    if (idx < FW * 32) {
      const int q = idx >> 5, cc = idx & 31;
      const int sq = drev(q), smm = drev((128 - q) & 127);
      const float a = re[sq * 32 + cc], b = im[sq * 32 + cc];
      const float cr = re[smm * 32 + cc], dr = -im[smm * 32 + cc];
      const float hsc = 0.00390625f;  // 0.5 * (1/128)
      const float xer = (a + cr) * hsc, xei = (b + dr) * hsc;
      const float xor_ = (b - dr) * hsc, xoi = (cr - a) * hsc;
      *(uint2*)(fq + (size_t)(bh * FW + q) * 768 + d0 + 2 * cc) =
          make_uint2(pk(xer, xei), pk(xor_, xoi));
    }
  }
}

// ---------------------------------------------------------------------------
// K2 (fused mid): H-FFT fwd -> MLP (MFMA) -> H-FFT inv, one WG per
// (b, fw, 96-chan block). 384 threads = 6 waves.
// FFT: thread (c, pp) owns h === pp (mod 4): 32 points, pos = pp+4j0+8m+32q.
//  - stages span-32 (over q) & span-8 (over m): in-register (proven code)
//  - stage span-2 + radix-2: cross-lane via __shfl_xor (lanes pp^2 -> xor 32,
//    pp^1 -> xor 16; lane = pp*16 + cL). Twiddles thread-constant.
// LDS: single 48KB bf16 [128][96 u32] tile (proven MFMA swizzle), reused for
// FFT-out / L1-in / hidden / L2-out / inv-FFT-in. 6 barriers total.
// ---------------------------------------------------------------------------
__global__ __launch_bounds__(384) void k_mid2(unsigned* __restrict__ fq,
    const bf16x8* __restrict__ wpb,
    const float* __restrict__ b1, const float* __restrict__ b2) {
  __shared__ __align__(16) char abuf[49152];   // 128 rows * 384 B
  __shared__ float twr[128], twi[128];
  const int t = threadIdx.x;
  const int blk = blockIdx.x, fw = blockIdx.y, b = blockIdx.z;
  TW_INIT();
  // FFT mapping: lane = pp*16 + cL (so pp^1 -> xor16, pp^2 -> xor32 in-wave)
  const int cG = t >> 6, pp = (t >> 4) & 3, cL = t & 15;
  const int c = cG * 16 + cL;  // channel 0..95
  unsigned* fp = fq + ((size_t)(b * 128) * FW + fw) * 768 + blk * 96;
  const size_t hs = (size_t)FW * 768;

  const float rS2 = 0.70710678118654752f;
  const int bp = pp & 1;
  const bool lo = (pp < 2);
  // own-output twiddles for cross-lane stage (fwd direction, W128^{16*bp*k}):
  //  lo: out j0=0 -> y0 (tw 1);   out j0=1 -> y2 (k=2)
  //  hi: out j0=0 -> y1 (k=1);    out j0=1 -> y3 (k=3)
  const float cA = lo ? 1.f : (bp ? rS2 : 1.f);
  const float sA = lo ? 0.f : (bp ? -rS2 : 0.f);
  const float cB = lo ? (bp ? 0.f : 1.f) : (bp ? -rS2 : 1.f);
  const float sB = lo ? (bp ? -1.f : 0.f) : (bp ? -rS2 : 0.f);

  float vr[2][4][4], vi[2][4][4];   // [j0][q][m], pos = pp + 4j0 + 8m + 32q

  // ---- load ----
#pragma unroll
  for (int j0 = 0; j0 < 2; ++j0)
#pragma unroll
    for (int q = 0; q < 4; ++q)
#pragma unroll
      for (int m = 0; m < 4; ++m) {
        const int pos = pp + 4 * j0 + 8 * m + 32 * q;
        const float2 v = upk(fp[(size_t)pos * hs + c]);
        vr[j0][q][m] = v.x; vi[j0][q][m] = v.y;
      }
  __syncthreads();  // B1: twiddle table ready

  // ---- fwd stage 1 (span 32, over q): np = pp + 4j0 + 8m ----
#pragma unroll
  for (int j0 = 0; j0 < 2; ++j0)
#pragma unroll
    for (int m = 0; m < 4; ++m) {
      const int np = pp + 4 * j0 + 8 * m;
      bf4reg<true>(vr[j0][0][m], vi[j0][0][m], vr[j0][1][m], vi[j0][1][m],
                   vr[j0][2][m], vi[j0][2][m], vr[j0][3][m], vi[j0][3][m],
                   twr[np], twi[np], twr[2 * np], twi[2 * np], twr[3 * np], twi[3 * np]);
    }
  // ---- fwd stage 2 (span 8, over m): np8 = pp + 4j0 ----
#pragma unroll
  for (int j0 = 0; j0 < 2; ++j0) {
    const int np8 = pp + 4 * j0;
#pragma unroll
    for (int q = 0; q < 4; ++q)
      bf4reg<true>(vr[j0][q][0], vi[j0][q][0], vr[j0][q][1], vi[j0][q][1],
                   vr[j0][q][2], vi[j0][q][2], vr[j0][q][3], vi[j0][q][3],
                   twr[4 * np8], twi[4 * np8], twr[8 * np8], twi[8 * np8],
                   twr[12 * np8], twi[12 * np8]);
  }
  // ---- fwd stage 3 (span 2): cross-lane pp^2 ----
#pragma unroll
  for (int q = 0; q < 4; ++q)
#pragma unroll
    for (int m = 0; m < 4; ++m) {
      const float sr = vr[0][q][m] + vr[1][q][m], si = vi[0][q][m] + vi[1][q][m];
      const float dr = vr[0][q][m] - vr[1][q][m], di = vi[0][q][m] - vi[1][q][m];
      const float txr = lo ? dr : sr, txi = lo ? di : si;
      const float rxr = __shfl_xor(txr, 32), rxi = __shfl_xor(txi, 32);
      if (lo) {  // own: v0=s (, v2=d sent); recv = partner's v1
        vr[0][q][m] = sr + rxr; vi[0][q][m] = si + rxi;            // y0
        const float ur = sr - rxr, ui = si - rxi;                  // v0 - v1
        vr[1][q][m] = ur * cB - ui * sB; vi[1][q][m] = ur * sB + ui * cB;  // y2
      } else {   // own: v3=d (, v1=s sent); recv = partner's v2
        const float u1r = rxr + di, u1i = rxi - dr;                // v2 - i v3
        const float u3r = rxr - di, u3i = rxi + dr;                // v2 + i v3
        vr[0][q][m] = u1r * cA - u1i * sA; vi[0][q][m] = u1r * sA + u1i * cA;  // y1
        vr[1][q][m] = u3r * cB - u3i * sB; vi[1][q][m] = u3r * sB + u3i * cB;  // y3
      }
    }
  // ---- fwd r2 (span 1): cross-lane pp^1 ----
#pragma unroll
  for (int j0 = 0; j0 < 2; ++j0)
#pragma unroll
    for (int q = 0; q < 4; ++q)
#pragma unroll
      for (int m = 0; m < 4; ++m) {
        const float rr = __shfl_xor(vr[j0][q][m], 16);
        const float ri = __shfl_xor(vi[j0][q][m], 16);
        vr[j0][q][m] = bp ? (rr - vr[j0][q][m]) : (vr[j0][q][m] + rr);
        vi[j0][q][m] = bp ? (ri - vi[j0][q][m]) : (vi[j0][q][m] + ri);
      }
  // ---- pack bf16 -> A-buf (proven MFMA swizzle) ----
#pragma unroll
  for (int j0 = 0; j0 < 2; ++j0)
#pragma unroll
    for (int q = 0; q < 4; ++q)
#pragma unroll
      for (int m = 0; m < 4; ++m) {
        const int row = pp + 4 * j0 + 8 * m + 32 * q;
        *(unsigned*)(abuf + row * 384 + ((4 * c) ^ ((row & 7) << 4))) =
            pk(vr[j0][q][m], vi[j0][q][m]);
      }
  __syncthreads();  // B2: A-buf ready

  // ======================= MLP (6 waves x 32 cols) =======================
  const int wv = t >> 6, l = t & 63;
  const int c16 = l & 15, g = l >> 4;
  const int n0 = wv * 32;
  f32x4 acc[8][2];
  float bs0 = b1[n0 + c16], bs1 = b1[n0 + 16 + c16];

#pragma unroll
  for (int mt = 0; mt < 8; ++mt) { acc[mt][0] = (f32x4)0.f; acc[mt][1] = (f32x4)0.f; }
  for (int kk = 0; kk < 6; ++kk) {
    bf16x8 a[8];
#pragma unroll
    for (int mt = 0; mt < 8; ++mt) {
      const int row = (mt << 4) + c16;
      a[mt] = *(const bf16x8*)(abuf + row * 384 + ((kk * 64 + g * 16) ^ ((row & 7) << 4)));
    }
    const bf16x8 bf0 = wpb[((n0 + c16) * 6 + kk) * 4 + g];
    const bf16x8 bf1 = wpb[((n0 + 16 + c16) * 6 + kk) * 4 + g];
#pragma unroll
    for (int mt = 0; mt < 8; ++mt) {
      acc[mt][0] = __builtin_amdgcn_mfma_f32_16x16x32_bf16(a[mt], bf0, acc[mt][0], 0, 0, 0);
      acc[mt][1] = __builtin_amdgcn_mfma_f32_16x16x32_bf16(a[mt], bf1, acc[mt][1], 0, 0, 0);
    }
  }
  __syncthreads();  // B3: layer-1 reads done
#pragma unroll
  for (int mt = 0; mt < 8; ++mt)
#pragma unroll
    for (int np = 0; np < 2; ++np) {
      const int col = n0 + np * 16 + c16;
      const float bb = np ? bs1 : bs0;
#pragma unroll
      for (int r = 0; r < 4; ++r) {
        const int row = (mt << 4) + (g << 2) + r;
        const float vv = fmaxf(acc[mt][np][r] + bb, 0.f);
        __hip_bfloat16 hb = __float2bfloat16(vv);
        *(unsigned short*)(abuf + row * 384 + ((2 * col) ^ ((row & 7) << 4))) = *(unsigned short*)&hb;
      }
    }
  __syncthreads();  // B4: hidden visible

  bs0 = b2[n0 + c16]; bs1 = b2[n0 + 16 + c16];
#pragma unroll
  for (int mt = 0; mt < 8; ++mt) { acc[mt][0] = (f32x4)0.f; acc[mt][1] = (f32x4)0.f; }
  const bf16x8* wpb2 = wpb + 4608;
  for (int kk = 0; kk < 6; ++kk) {
    bf16x8 a[8];
#pragma unroll
    for (int mt = 0; mt < 8; ++mt) {
      const int row = (mt << 4) + c16;
      a[mt] = *(const bf16x8*)(abuf + row * 384 + ((kk * 64 + g * 16) ^ ((row & 7) << 4)));
    }
    const bf16x8 bf0 = wpb2[((n0 + c16) * 6 + kk) * 4 + g];
    const bf16x8 bf1 = wpb2[((n0 + 16 + c16) * 6 + kk) * 4 + g];
#pragma unroll
    for (int mt = 0; mt < 8; ++mt) {
      acc[mt][0] = __builtin_amdgcn_mfma_f32_16x16x32_bf16(a[mt], bf0, acc[mt][0], 0, 0, 0);
      acc[mt][1] = __builtin_amdgcn_mfma_f32_16x16x32_bf16(a[mt], bf1, acc[mt][1], 0, 0, 0);
    }
  }
  __syncthreads();  // B5: layer-2 reads done
#pragma unroll
  for (int mt = 0; mt < 8; ++mt)
#pragma unroll
    for (int np = 0; np < 2; ++np) {
      const int col = n0 + np * 16 + c16;
      const float bb = np ? bs1 : bs0;
#pragma unroll
      for (int r = 0; r < 4; ++r) {
        const int row = (mt << 4) + (g << 2) + r;
        float vv = acc[mt][np][r] + bb;
        vv = (vv > THRESH_) ? (vv - THRESH_) : ((vv < -THRESH_) ? (vv + THRESH_) : 0.f);
        __hip_bfloat16 hb = __float2bfloat16(vv);
        *(unsigned short*)(abuf + row * 384 + ((2 * col) ^ ((row & 7) << 4))) = *(unsigned short*)&hb;
      }
    }
  __syncthreads();  // B6: MLP output in A-buf

  // ======================= inverse H-FFT =======================
#pragma unroll
  for (int j0 = 0; j0 < 2; ++j0)
#pragma unroll
    for (int q = 0; q < 4; ++q)
#pragma unroll
      for (int m = 0; m < 4; ++m) {
        const int row = pp + 4 * j0 + 8 * m + 32 * q;
        const float2 v = upk(*(unsigned*)(abuf + row * 384 + ((4 * c) ^ ((row & 7) << 4))));
        vr[j0][q][m] = v.x; vi[j0][q][m] = v.y;
      }
  // ---- inv r2: cross-lane pp^1 (same butterfly) ----
#pragma unroll
  for (int j0 = 0; j0 < 2; ++j0)
#pragma unroll
    for (int q = 0; q < 4; ++q)
#pragma unroll
      for (int m = 0; m < 4; ++m) {
        const float rr = __shfl_xor(vr[j0][q][m], 16);
        const float ri = __shfl_xor(vi[j0][q][m], 16);
        vr[j0][q][m] = bp ? (rr - vr[j0][q][m]) : (vr[j0][q][m] + rr);
        vi[j0][q][m] = bp ? (ri - vi[j0][q][m]) : (vi[j0][q][m] + ri);
      }
  // ---- inv stage 3: conj own twiddles, cross-lane pp^2 ----
#pragma unroll
  for (int q = 0; q < 4; ++q)
#pragma unroll
    for (int m = 0; m < 4; ++m) {
      // t = y * conj(tw): tr = yr*c + yi*s; ti = yi*c - yr*s
      const float a0r = vr[0][q][m] * cA + vi[0][q][m] * sA;
      const float a0i = vi[0][q][m] * cA - vr[0][q][m] * sA;
      const float a1r = vr[1][q][m] * cB + vi[1][q][m] * sB;
      const float a1i = vi[1][q][m] * cB - vr[1][q][m] * sB;
      const float wsr = a0r + a1r, wsi = a0i + a1i;   // w0 (lo) / w1 (hi)
      const float wdr = a0r - a1r, wdi = a0i - a1i;   // w2 (lo) / w3 (hi)
      const float txr = lo ? wdr : wsr, txi = lo ? wdi : wsi;
      const float rxr = __shfl_xor(txr, 32), rxi = __shfl_xor(txi, 32);
      if (lo) {  // recv = w1
        vr[0][q][m] = wsr + rxr; vi[0][q][m] = wsi + rxi;   // x0
        vr[1][q][m] = wsr - rxr; vi[1][q][m] = wsi - rxi;   // x2
      } else {   // recv = w2, own wd = w3
        vr[0][q][m] = rxr - wdi; vi[0][q][m] = rxi + wdr;   // x1 = w2 + i w3
        vr[1][q][m] = rxr + wdi; vi[1][q][m] = rxi - wdr;   // x3 = w2 - i w3
      }
    }
  // ---- inv stage 2 (over m): np8 = pp + 4j0 ----
#pragma unroll
  for (int j0 = 0; j0 < 2; ++j0) {
    const int np8 = pp + 4 * j0;
#pragma unroll
    for (int q = 0; q < 4; ++q)
      ibf4r(vr[j0][q][0], vi[j0][q][0], vr[j0][q][1], vi[j0][q][1],
            vr[j0][q][2], vi[j0][q][2], vr[j0][q][3], vi[j0][q][3],
            twr[4 * np8], twi[4 * np8], twr[8 * np8], twi[8 * np8],
            twr[12 * np8], twi[12 * np8]);
  }
  // ---- inv stage 1 (over q): np = pp + 4j0 + 8m ----
#pragma unroll
  for (int j0 = 0; j0 < 2; ++j0)
#pragma unroll
    for (int m = 0; m < 4; ++m) {
      const int np = pp + 4 * j0 + 8 * m;
      ibf4r(vr[j0][0][m], vi[j0][0][m], vr[j0][1][m], vi[j0][1][m],
            vr[j0][2][m], vi[j0][2][m], vr[j0][3][m], vi[j0][3][m],
            twr[np], twi[np], twr[2 * np], twi[2 * np], twr[3 * np], twi[3 * np]);
    }
  // ---- store natural-h bf16 fq ----
#pragma unroll
  for (int j0 = 0; j0 < 2; ++j0)
#pragma unroll
    for (int q = 0; q < 4; ++q)
#pragma unroll
      for (int m = 0; m < 4; ++m) {
        const int pos = pp + 4 * j0 + 8 * m + 32 * q;
        fp[(size_t)pos * hs + c] = pk(vr[j0][q][m], vi[j0][q][m]);
      }
}

// ---------------------------------------------------------------------------
// K3: inverse rFFT over W, two-phase register fusion + direct global store
// with skip-add. Sample for slot s is drevinv(s). grid (512, 12). (round 7)
// ---------------------------------------------------------------------------
__global__ __launch_bounds__(TPB) void k_inv_w(const unsigned* __restrict__ fq,
                                               const float* __restrict__ x,
                                               float* __restrict__ out) {
  __shared__ float re[4096], im[4096], twr[128], twi[128];
  const int t = threadIdx.x;
  const int bh = blockIdx.x;
  const int d0 = blockIdx.y << 6;
  TW_INIT();
  const int c = t & 31, p = t >> 5;
  const float sc = 0.0078125f;  // 1/128

#pragma unroll
  for (int it = 0; it < 9; ++it) {
    const int idx = it * TPB + t;
    if (idx < FW * 32) {
      const int q = idx >> 5, cc = idx & 31;
      const uint2 vv = *(const uint2*)(fq + (size_t)(bh * FW + q) * 768 + d0 + 2 * cc);
      const float2 e = upk(vv.x), o = upk(vv.y);
      re[q * 32 + cc] = (e.x - o.y) * sc; im[q * 32 + cc] = (e.y + o.x) * sc;
      if (q >= 1 && q <= 63) {
        re[(128 - q) * 32 + cc] = (e.x + o.y) * sc;
        im[(128 - q) * 32 + cc] = (o.x - e.y) * sc;
      }
    }
  }
  __syncthreads();

  float vr[4][4], vi[4][4];
#pragma unroll
  for (int q = 0; q < 4; ++q)
#pragma unroll
    for (int m = 0; m < 4; ++m) {
      const int pos = p + 8 * m + 32 * q;
      vr[q][m] = re[pos * 32 + c]; vi[q][m] = im[pos * 32 + c];
    }
#pragma unroll
  for (int m = 0; m < 4; ++m) {
    const int np = p + 8 * m;
    bf4reg<false>(vr[0][m], vi[0][m], vr[1][m], vi[1][m], vr[2][m], vi[2][m], vr[3][m], vi[3][m],
                  twr[np], -twi[np], twr[2 * np], -twi[2 * np], twr[3 * np], -twi[3 * np]);
  }
#pragma unroll
  for (int q = 0; q < 4; ++q)
    bf4reg<false>(vr[q][0], vi[q][0], vr[q][1], vi[q][1], vr[q][2], vi[q][2], vr[q][3], vi[q][3],
                  twr[4 * p], -twi[4 * p], twr[8 * p], -twi[8 * p], twr[12 * p], -twi[12 * p]);
#pragma unroll
  for (int q = 0; q < 4; ++q)
#pragma unroll
    for (int m = 0; m < 4; ++m) {
      const int pos = p + 8 * m + 32 * q;
      re[pos * 32 + c] = vr[q][m]; im[pos * 32 + c] = vi[q][m];
    }
  __syncthreads();

  const float2* xv = (const float2*)x;
  float2* ov = (float2*)out;
#pragma unroll
  for (int half = 0; half < 2; ++half) {
    const int g = 8 * half + p;
    float wr8[8], wi8[8];
#pragma unroll
    for (int j = 0; j < 8; ++j) { wr8[j] = re[(8 * g + j) * 32 + c]; wi8[j] = im[(8 * g + j) * 32 + c]; }
    bf4reg<false>(wr8[0], wi8[0], wr8[2], wi8[2], wr8[4], wi8[4], wr8[6], wi8[6],
                  1.f, 0.f, 1.f, 0.f, 1.f, 0.f);
    bf4reg<false>(wr8[1], wi8[1], wr8[3], wi8[3], wr8[5], wi8[5], wr8[7], wi8[7],
                  twr[16], -twi[16], twr[32], -twi[32], twr[48], -twi[48]);
#pragma unroll
    for (int j = 0; j < 8; j += 2) {
      const float ar = wr8[j], ai = wi8[j], br = wr8[j + 1], bi = wi8[j + 1];
      wr8[j] = ar + br; wi8[j] = ai + bi;
      wr8[j + 1] = ar - br; wi8[j + 1] = ai - bi;
    }
#pragma unroll
    for (int j = 0; j < 8; ++j) {
      const int w = drevinv(8 * g + j);
      const size_t fi = (size_t)bh * 49152 + w * 384 + (d0 >> 1) + c;
      const float2 s = xv[fi];
      ov[fi] = make_float2(wr8[j] + s.x, wi8[j] + s.y);
    }
  }
}

// ---------------------------------------------------------------------------
extern "C" void kernel_launch(void* const* d_in, const int* in_sizes, int n_in,
                              void* d_out, int out_size, void* d_ws, size_t ws_size,
                              hipStream_t stream) {
  const float* x   = (const float*)d_in[0];
  const float* w1r = (const float*)d_in[1];
  const float* w1i = (const float*)d_in[2];
  const float* b1  = (const float*)d_in[3];
  const float* w2r = (const float*)d_in[4];
  const float* w2i = (const float*)d_in[5];
  const float* b2  = (const float*)d_in[6];
  unsigned* fq = (unsigned*)d_ws;
  float* out = (float*)d_out;

  const size_t need = (size_t)BH_ * FW * 768 * 4;  // 102,236,160 B
  if (ws_size < need) {
    fprintf(stderr, "kernel_launch: ws too small (%zu < %zu)\n", ws_size, need);
    return;
  }

  // packed bf16 weights at start of d_out (fully overwritten by k_inv_w later)
  unsigned short* wp = (unsigned short*)d_out;

  k_wpack<<<dim3(288), TPB, 0, stream>>>(w1r, w1i, w2r, w2i, wp);
  k_fwd_w<<<dim3(BH_, 12), TPB, 0, stream>>>(x, fq);
  k_mid2<<<dim3(8, FW, B_), 384, 0, stream>>>(fq, (const bf16x8*)wp, b1, b2);
  k_inv_w<<<dim3(BH_, 12), TPB, 0, stream>>>(fq, x, out);
}

// Round 10
// 309.923 us; speedup vs baseline: 1.3190x; 1.3190x over previous
//
#include <hip/hip_runtime.h>
#include <hip/hip_bf16.h>
#include <cstdio>

#define TPB 256
#define B_ 4
#define H_ 128
#define W_ 128
#define D_ 768
#define FW 65
#define BH_ 512                  // B_*H_
#define THRESH_ 0.01f
#define NEG_TWO_PI_OVER_128 (-0.04908738521234052f)

typedef short bf16x8 __attribute__((ext_vector_type(8)));
typedef float f32x4 __attribute__((ext_vector_type(4)));
typedef float f32x2 __attribute__((ext_vector_type(2)));

// fq (in d_ws): one u32 per (point, channel) = packed (bf16 re, bf16 im)
//   u32 index = ((b*128 + h)*65 + fw)*768 + d
// Mixed-radix 128 = 4*4*4*2 DIF; slot(k) = digit-reverse:
//   drev(k) = ((k&3)<<5) | (((k>>2)&3)<<3) | (((k>>4)&3)<<1) | ((k>>6)&1)
// drev is NOT an involution; inverse is drevinv.

__device__ __forceinline__ unsigned pk(float lo, float hi) {
  __hip_bfloat162 h2 = __float22bfloat162_rn(make_float2(lo, hi));
  return *(unsigned*)&h2;
}
__device__ __forceinline__ float2 upk(unsigned u) {
  return __bfloat1622float2(*(__hip_bfloat162*)&u);
}
__device__ __forceinline__ int drev(int k) {
  return ((k & 3) << 5) | (((k >> 2) & 3) << 3) | (((k >> 4) & 3) << 1) | ((k >> 6) & 1);
}
__device__ __forceinline__ int drevinv(int s) {
  return ((s & 1) << 6) | (((s >> 1) & 3) << 4) | (((s >> 3) & 3) << 2) | ((s >> 5) & 3);
}

// register radix-4 DIF butterfly. FWD: e^-i; !FWD: e^+i (pass negated twi).
template <bool FWD>
__device__ __forceinline__ void bf4reg(float& x0r, float& x0i, float& x1r, float& x1i,
                                       float& x2r, float& x2i, float& x3r, float& x3i,
                                       float c1, float s1, float c2, float s2, float c3, float s3) {
  const float v0r = x0r + x2r, v0i = x0i + x2i, v2r = x0r - x2r, v2i = x0i - x2i;
  const float v1r = x1r + x3r, v1i = x1i + x3i, v3r = x1r - x3r, v3i = x1i - x3i;
  float u1r, u1i, u3r, u3i;
  if (FWD) { u1r = v2r + v3i; u1i = v2i - v3r; u3r = v2r - v3i; u3i = v2i + v3r; }
  else     { u1r = v2r - v3i; u1i = v2i + v3r; u3r = v2r + v3i; u3i = v2i - v3r; }
  const float u2r = v0r - v1r, u2i = v0i - v1i;
  x0r = v0r + v1r;            x0i = v0i + v1i;
  x1r = u1r * c1 - u1i * s1;  x1i = u1r * s1 + u1i * c1;
  x2r = u2r * c2 - u2i * s2;  x2i = u2r * s2 + u2i * c2;
  x3r = u3r * c3 - u3i * s3;  x3i = u3r * s3 + u3i * c3;
}

// register inverse radix-4 butterfly (DIT: conj-twiddle inputs, e^+i DFT4)
__device__ __forceinline__ void ibf4r(float& x0r, float& x0i, float& x1r, float& x1i,
                                      float& x2r, float& x2i, float& x3r, float& x3i,
                                      float c1, float s1, float c2, float s2, float c3, float s3) {
  const float t0r = x0r, t0i = x0i;
  const float t1r = x1r * c1 + x1i * s1, t1i = x1i * c1 - x1r * s1;
  const float t2r = x2r * c2 + x2i * s2, t2i = x2i * c2 - x2r * s2;
  const float t3r = x3r * c3 + x3i * s3, t3i = x3i * c3 - x3r * s3;
  const float w0r = t0r + t2r, w0i = t0i + t2i, w2r = t0r - t2r, w2i = t0i - t2i;
  const float w1r = t1r + t3r, w1i = t1i + t3i, w3r = t1r - t3r, w3i = t1i - t3i;
  x0r = w0r + w1r; x0i = w0i + w1i;
  x1r = w2r - w3i; x1i = w2i + w3r;
  x2r = w0r - w1r; x2i = w0i - w1i;
  x3r = w2r + w3i; x3i = w2i - w3r;
}

#define TW_INIT() do { if (t < 128) { float s_, c_; \
    __sincosf(NEG_TWO_PI_OVER_128 * (float)t, &s_, &c_); twr[t] = c_; twi[t] = s_; } } while (0)

// ---------------------------------------------------------------------------
// K0: pack complex weights into bf16 B-fragment order (block form Wc).
// ---------------------------------------------------------------------------
__global__ __launch_bounds__(TPB) void k_wpack(const float* __restrict__ w1r,
                                               const float* __restrict__ w1i,
                                               const float* __restrict__ w2r,
                                               const float* __restrict__ w2i,
                                               unsigned short* __restrict__ wp) {
  const int tid = blockIdx.x * TPB + threadIdx.x;
  if (tid >= 2 * 36864) return;
  const int L = tid / 36864, rem = tid % 36864;
  const int n = rem / 192, k = rem % 192;
  const int c = k >> 1, s = k & 1, o = n >> 1, t = n & 1;
  const float* wr = L ? w2r : w1r;
  const float* wi = L ? w2i : w1i;
  const float val = (s == 0) ? (t == 0 ? wr[o * 96 + c] : wi[o * 96 + c])
                             : (t == 0 ? -wi[o * 96 + c] : wr[o * 96 + c]);
  __hip_bfloat16 h = __float2bfloat16(val);
  const int idx = ((n * 6 + (k >> 5)) * 4 + ((k >> 3) & 3)) * 8 + (k & 7);
  wp[L * 36864 + idx] = *(unsigned short*)&h;
}

// ---------------------------------------------------------------------------
// K1: forward rFFT over W via real-pair packing, two-phase register fusion.
// x loads nontemporal (streamed once; keep L3 for fq). grid (512, 12).
// ---------------------------------------------------------------------------
__global__ __launch_bounds__(TPB) void k_fwd_w(const float* __restrict__ x,
                                               unsigned* __restrict__ fq) {
  __shared__ float re[4096], im[4096], twr[128], twi[128];
  const int t = threadIdx.x;
  const int bh = blockIdx.x;
  const int d0 = blockIdx.y << 6;
  TW_INIT();
  const int c = t & 31, p = t >> 5;
  const f32x2* xp = (const f32x2*)(x + (size_t)bh * 98304 + d0);

  float vr[4][4], vi[4][4];
#pragma unroll
  for (int q = 0; q < 4; ++q)
#pragma unroll
    for (int m = 0; m < 4; ++m) {
      const f32x2 v = __builtin_nontemporal_load(&xp[(p + 8 * m + 32 * q) * 384 + c]);
      vr[q][m] = v.x; vi[q][m] = v.y;
    }
  __syncthreads();
#pragma unroll
  for (int m = 0; m < 4; ++m) {
    const int np = p + 8 * m;
    bf4reg<true>(vr[0][m], vi[0][m], vr[1][m], vi[1][m], vr[2][m], vi[2][m], vr[3][m], vi[3][m],
                 twr[np], twi[np], twr[2 * np], twi[2 * np], twr[3 * np], twi[3 * np]);
  }
#pragma unroll
  for (int q = 0; q < 4; ++q)
    bf4reg<true>(vr[q][0], vi[q][0], vr[q][1], vi[q][1], vr[q][2], vi[q][2], vr[q][3], vi[q][3],
                 twr[4 * p], twi[4 * p], twr[8 * p], twi[8 * p], twr[12 * p], twi[12 * p]);
#pragma unroll
  for (int q = 0; q < 4; ++q)
#pragma unroll
    for (int m = 0; m < 4; ++m) {
      const int pos = p + 8 * m + 32 * q;
      re[pos * 32 + c] = vr[q][m]; im[pos * 32 + c] = vi[q][m];
    }
  __syncthreads();

#pragma unroll
  for (int half = 0; half < 2; ++half) {
    const int g = 8 * half + p;
    float wr8[8], wi8[8];
#pragma unroll
    for (int j = 0; j < 8; ++j) { wr8[j] = re[(8 * g + j) * 32 + c]; wi8[j] = im[(8 * g + j) * 32 + c]; }
    bf4reg<true>(wr8[0], wi8[0], wr8[2], wi8[2], wr8[4], wi8[4], wr8[6], wi8[6],
                 1.f, 0.f, 1.f, 0.f, 1.f, 0.f);
    bf4reg<true>(wr8[1], wi8[1], wr8[3], wi8[3], wr8[5], wi8[5], wr8[7], wi8[7],
                 twr[16], twi[16], twr[32], twi[32], twr[48], twi[48]);
#pragma unroll
    for (int j = 0; j < 8; j += 2) {
      const float ar = wr8[j], ai = wi8[j], br = wr8[j + 1], bi = wi8[j + 1];
      wr8[j] = ar + br; wi8[j] = ai + bi;
      wr8[j + 1] = ar - br; wi8[j + 1] = ai - bi;
    }
#pragma unroll
    for (int j = 0; j < 8; ++j) {
      re[(8 * g + j) * 32 + c] = wr8[j]; im[(8 * g + j) * 32 + c] = wi8[j];
    }
  }
  __syncthreads();

#pragma unroll
  for (int it = 0; it < 9; ++it) {
    const int idx = it * TPB + t;
    if (idx < FW * 32) {
      const int q = idx >> 5, cc = idx & 31;
      const int sq = drev(q), smm = drev((128 - q) & 127);
      const float a = re[sq * 32 + cc], b = im[sq * 32 + cc];
      const float cr = re[smm * 32 + cc], dr = -im[smm * 32 + cc];
      const float hsc = 0.00390625f;  // 0.5 * (1/128)
      const float xer = (a + cr) * hsc, xei = (b + dr) * hsc;
      const float xor_ = (b - dr) * hsc, xoi = (cr - a) * hsc;
      *(uint2*)(fq + (size_t)(bh * FW + q) * 768 + d0 + 2 * cc) =
          make_uint2(pk(xer, xei), pk(xor_, xoi));
    }
  }
}

// ---------------------------------------------------------------------------
// K2a: forward complex FFT over H, in-place; output digit-reversed slots.
// Two-stage register fusion. grid (4, 65, 24).
// ---------------------------------------------------------------------------
__global__ __launch_bounds__(TPB) void k_fwd_h(unsigned* __restrict__ fq) {
  __shared__ float re[4096], im[4096], twr[128], twi[128];
  const int t = threadIdx.x;
  const int b = blockIdx.x, fw = blockIdx.y, d0 = blockIdx.z << 5;
  TW_INIT();
  unsigned* fp = fq + (size_t)(b * 128 * FW + fw) * 768 + d0;
  const int c = t & 31, p = t >> 5;
  const size_t hs = (size_t)FW * 768;

  float vr[4][4], vi[4][4];
#pragma unroll
  for (int q = 0; q < 4; ++q)
#pragma unroll
    for (int m = 0; m < 4; ++m) {
      const float2 v = upk(fp[(size_t)(p + 8 * m + 32 * q) * hs + c]);
      vr[q][m] = v.x; vi[q][m] = v.y;
    }
  __syncthreads();
#pragma unroll
  for (int m = 0; m < 4; ++m) {
    const int np = p + 8 * m;
    bf4reg<true>(vr[0][m], vi[0][m], vr[1][m], vi[1][m], vr[2][m], vi[2][m], vr[3][m], vi[3][m],
                 twr[np], twi[np], twr[2 * np], twi[2 * np], twr[3 * np], twi[3 * np]);
  }
#pragma unroll
  for (int q = 0; q < 4; ++q)
    bf4reg<true>(vr[q][0], vi[q][0], vr[q][1], vi[q][1], vr[q][2], vi[q][2], vr[q][3], vi[q][3],
                 twr[4 * p], twi[4 * p], twr[8 * p], twi[8 * p], twr[12 * p], twi[12 * p]);
#pragma unroll
  for (int q = 0; q < 4; ++q)
#pragma unroll
    for (int m = 0; m < 4; ++m) {
      const int pos = p + 8 * m + 32 * q;
      re[pos * 32 + c] = vr[q][m]; im[pos * 32 + c] = vi[q][m];
    }
  __syncthreads();

#pragma unroll
  for (int half = 0; half < 2; ++half) {
    const int g = 8 * half + p;
    float wr8[8], wi8[8];
#pragma unroll
    for (int j = 0; j < 8; ++j) { wr8[j] = re[(8 * g + j) * 32 + c]; wi8[j] = im[(8 * g + j) * 32 + c]; }
    bf4reg<true>(wr8[0], wi8[0], wr8[2], wi8[2], wr8[4], wi8[4], wr8[6], wi8[6],
                 1.f, 0.f, 1.f, 0.f, 1.f, 0.f);
    bf4reg<true>(wr8[1], wi8[1], wr8[3], wi8[3], wr8[5], wi8[5], wr8[7], wi8[7],
                 twr[16], twi[16], twr[32], twi[32], twr[48], twi[48]);
#pragma unroll
    for (int j = 0; j < 8; j += 2) {
      const float ar = wr8[j], ai = wi8[j], br = wr8[j + 1], bi = wi8[j + 1];
      wr8[j] = ar + br; wi8[j] = ai + bi;
      wr8[j + 1] = ar - br; wi8[j + 1] = ai - bi;
    }
#pragma unroll
    for (int j = 0; j < 8; ++j)
      fp[(size_t)(8 * g + j) * hs + c] = pk(wr8[j], wi8[j]);
  }
}

// ---------------------------------------------------------------------------
// K2b: MFMA MLP, in-place on bf16 fq. M-tile 64 (24 KB LDS).
// ---------------------------------------------------------------------------
__global__ __launch_bounds__(TPB, 4) void k_mlp_mfma(unsigned* __restrict__ fq,
    const bf16x8* __restrict__ wpb,
    const float* __restrict__ b1, const float* __restrict__ b2) {
  __shared__ __align__(16) char lds[24576];   // 64 rows * 384 B
  const int t  = threadIdx.x;
  const int wv = t >> 6;
  const int l  = t & 63;
  const int c16 = l & 15, g = l >> 4, low3 = l & 7;
  const int n0 = wv * 48;
  const int P0 = blockIdx.x << 6;

  const uint4* src = (const uint4*)(fq + (size_t)P0 * 96);
#pragma unroll
  for (int it = 0; it < 6; ++it) {
    const int q = it * TPB + t;                 // 1536 uint4s
    const int row = q / 24, f = q % 24;
    *(uint4*)(lds + row * 384 + ((f * 16) ^ ((row & 7) << 4))) = src[q];
  }
  __syncthreads();

  f32x4 acc[4][3];
  float bs0 = b1[n0 + c16], bs1 = b1[n0 + 16 + c16], bs2 = b1[n0 + 32 + c16];

#pragma unroll
  for (int mt = 0; mt < 4; ++mt)
#pragma unroll
    for (int np = 0; np < 3; ++np) acc[mt][np] = (f32x4)0.f;
  for (int kk = 0; kk < 6; ++kk) {
    bf16x8 a[4];
#pragma unroll
    for (int mt = 0; mt < 4; ++mt) {
      const int row = (mt << 4) + c16;
      a[mt] = *(const bf16x8*)(lds + row * 384 + ((kk * 64 + g * 16) ^ (low3 << 4)));
    }
    bf16x8 bfr[3];
#pragma unroll
    for (int np = 0; np < 3; ++np) bfr[np] = wpb[((n0 + np * 16 + c16) * 6 + kk) * 4 + g];
#pragma unroll
    for (int mt = 0; mt < 4; ++mt)
#pragma unroll
      for (int np = 0; np < 3; ++np)
        acc[mt][np] = __builtin_amdgcn_mfma_f32_16x16x32_bf16(a[mt], bfr[np], acc[mt][np], 0, 0, 0);
  }
  __syncthreads();
#pragma unroll
  for (int mt = 0; mt < 4; ++mt)
#pragma unroll
    for (int np = 0; np < 3; ++np) {
      const int col = n0 + np * 16 + c16;
      const float bb = np == 0 ? bs0 : (np == 1 ? bs1 : bs2);
#pragma unroll
      for (int r = 0; r < 4; ++r) {
        const int row = (mt << 4) + (g << 2) + r;
        const float vv = fmaxf(acc[mt][np][r] + bb, 0.f);
        __hip_bfloat16 hb = __float2bfloat16(vv);
        *(unsigned short*)(lds + row * 384 + ((2 * col) ^ ((row & 7) << 4))) = *(unsigned short*)&hb;
      }
    }
  __syncthreads();

  bs0 = b2[n0 + c16]; bs1 = b2[n0 + 16 + c16]; bs2 = b2[n0 + 32 + c16];
#pragma unroll
  for (int mt = 0; mt < 4; ++mt)
#pragma unroll
    for (int np = 0; np < 3; ++np) acc[mt][np] = (f32x4)0.f;
  const bf16x8* wpb2 = wpb + 4608;
  for (int kk = 0; kk < 6; ++kk) {
    bf16x8 a[4];
#pragma unroll
    for (int mt = 0; mt < 4; ++mt) {
      const int row = (mt << 4) + c16;
      a[mt] = *(const bf16x8*)(lds + row * 384 + ((kk * 64 + g * 16) ^ (low3 << 4)));
    }
    bf16x8 bfr[3];
#pragma unroll
    for (int np = 0; np < 3; ++np) bfr[np] = wpb2[((n0 + np * 16 + c16) * 6 + kk) * 4 + g];
#pragma unroll
    for (int mt = 0; mt < 4; ++mt)
#pragma unroll
      for (int np = 0; np < 3; ++np)
        acc[mt][np] = __builtin_amdgcn_mfma_f32_16x16x32_bf16(a[mt], bfr[np], acc[mt][np], 0, 0, 0);
  }
  unsigned short* fq16 = (unsigned short*)fq;
#pragma unroll
  for (int mt = 0; mt < 4; ++mt)
#pragma unroll
    for (int np = 0; np < 3; ++np) {
      const int col = n0 + np * 16 + c16;
      const float bb = np == 0 ? bs0 : (np == 1 ? bs1 : bs2);
#pragma unroll
      for (int r = 0; r < 4; ++r) {
        const int row = (mt << 4) + (g << 2) + r;
        float vv = acc[mt][np][r] + bb;
        vv = (vv > THRESH_) ? (vv - THRESH_) : ((vv < -THRESH_) ? (vv + THRESH_) : 0.f);
        __hip_bfloat16 hb = __float2bfloat16(vv);
        fq16[(size_t)(P0 + row) * 192 + col] = *(unsigned short*)&hb;
      }
    }
}

// ---------------------------------------------------------------------------
// K2c: inverse FFT over H (DIT, digit-reversed in, natural out, e^+i),
// two-stage register fusion. In-place bf16. grid (4, 65, 24).
// ---------------------------------------------------------------------------
__global__ __launch_bounds__(TPB) void k_inv_h(unsigned* __restrict__ fq) {
  __shared__ float re[4096], im[4096], twr[128], twi[128];
  const int t = threadIdx.x;
  const int b = blockIdx.x, fw = blockIdx.y, d0 = blockIdx.z << 5;
  TW_INIT();
  unsigned* fp = fq + (size_t)(b * 128 * FW + fw) * 768 + d0;
  const int c = t & 31, p = t >> 5;
  const size_t hs = (size_t)FW * 768;

#pragma unroll
  for (int half = 0; half < 2; ++half) {
    const int g = 8 * half + p;
    float wr8[8], wi8[8];
#pragma unroll
    for (int j = 0; j < 8; ++j) {
      const float2 v = upk(fp[(size_t)(8 * g + j) * hs + c]);
      wr8[j] = v.x; wi8[j] = v.y;
    }
    if (half == 0) __syncthreads();  // twiddle table ready (once)
#pragma unroll
    for (int j = 0; j < 8; j += 2) {
      const float ar = wr8[j], ai = wi8[j], br = wr8[j + 1], bi = wi8[j + 1];
      wr8[j] = ar + br; wi8[j] = ai + bi;
      wr8[j + 1] = ar - br; wi8[j + 1] = ai - bi;
    }
    ibf4r(wr8[0], wi8[0], wr8[2], wi8[2], wr8[4], wi8[4], wr8[6], wi8[6],
          1.f, 0.f, 1.f, 0.f, 1.f, 0.f);
    ibf4r(wr8[1], wi8[1], wr8[3], wi8[3], wr8[5], wi8[5], wr8[7], wi8[7],
          twr[16], twi[16], twr[32], twi[32], twr[48], twi[48]);
#pragma unroll
    for (int j = 0; j < 8; ++j) {
      re[(8 * g + j) * 32 + c] = wr8[j]; im[(8 * g + j) * 32 + c] = wi8[j];
    }
  }
  __syncthreads();

  float vr[4][4], vi[4][4];
#pragma unroll
  for (int q = 0; q < 4; ++q)
#pragma unroll
    for (int m = 0; m < 4; ++m) {
      const int pos = p + 8 * m + 32 * q;
      vr[q][m] = re[pos * 32 + c]; vi[q][m] = im[pos * 32 + c];
    }
#pragma unroll
  for (int q = 0; q < 4; ++q)
    ibf4r(vr[q][0], vi[q][0], vr[q][1], vi[q][1], vr[q][2], vi[q][2], vr[q][3], vi[q][3],
          twr[4 * p], twi[4 * p], twr[8 * p], twi[8 * p], twr[12 * p], twi[12 * p]);
#pragma unroll
  for (int m = 0; m < 4; ++m) {
    const int np = p + 8 * m;
    ibf4r(vr[0][m], vi[0][m], vr[1][m], vi[1][m], vr[2][m], vi[2][m], vr[3][m], vi[3][m],
          twr[np], twi[np], twr[2 * np], twi[2 * np], twr[3 * np], twi[3 * np]);
  }
#pragma unroll
  for (int q = 0; q < 4; ++q)
#pragma unroll
    for (int m = 0; m < 4; ++m)
      fp[(size_t)(p + 8 * m + 32 * q) * hs + c] = pk(vr[q][m], vi[q][m]);
}

// ---------------------------------------------------------------------------
// K3: inverse rFFT over W, two-phase register fusion + direct global store
// with skip-add. x loads and out stores nontemporal. grid (512, 12).
// ---------------------------------------------------------------------------
__global__ __launch_bounds__(TPB) void k_inv_w(const unsigned* __restrict__ fq,
                                               const float* __restrict__ x,
                                               float* __restrict__ out) {
  __shared__ float re[4096], im[4096], twr[128], twi[128];
  const int t = threadIdx.x;
  const int bh = blockIdx.x;
  const int d0 = blockIdx.y << 6;
  TW_INIT();
  const int c = t & 31, p = t >> 5;
  const float sc = 0.0078125f;  // 1/128

#pragma unroll
  for (int it = 0; it < 9; ++it) {
    const int idx = it * TPB + t;
    if (idx < FW * 32) {
      const int q = idx >> 5, cc = idx & 31;
      const uint2 vv = *(const uint2*)(fq + (size_t)(bh * FW + q) * 768 + d0 + 2 * cc);
      const float2 e = upk(vv.x), o = upk(vv.y);
      re[q * 32 + cc] = (e.x - o.y) * sc; im[q * 32 + cc] = (e.y + o.x) * sc;
      if (q >= 1 && q <= 63) {
        re[(128 - q) * 32 + cc] = (e.x + o.y) * sc;
        im[(128 - q) * 32 + cc] = (o.x - e.y) * sc;
      }
    }
  }
  __syncthreads();

  float vr[4][4], vi[4][4];
#pragma unroll
  for (int q = 0; q < 4; ++q)
#pragma unroll
    for (int m = 0; m < 4; ++m) {
      const int pos = p + 8 * m + 32 * q;
      vr[q][m] = re[pos * 32 + c]; vi[q][m] = im[pos * 32 + c];
    }
#pragma unroll
  for (int m = 0; m < 4; ++m) {
    const int np = p + 8 * m;
    bf4reg<false>(vr[0][m], vi[0][m], vr[1][m], vi[1][m], vr[2][m], vi[2][m], vr[3][m], vi[3][m],
                  twr[np], -twi[np], twr[2 * np], -twi[2 * np], twr[3 * np], -twi[3 * np]);
  }
#pragma unroll
  for (int q = 0; q < 4; ++q)
    bf4reg<false>(vr[q][0], vi[q][0], vr[q][1], vi[q][1], vr[q][2], vi[q][2], vr[q][3], vi[q][3],
                  twr[4 * p], -twi[4 * p], twr[8 * p], -twi[8 * p], twr[12 * p], -twi[12 * p]);
#pragma unroll
  for (int q = 0; q < 4; ++q)
#pragma unroll
    for (int m = 0; m < 4; ++m) {
      const int pos = p + 8 * m + 32 * q;
      re[pos * 32 + c] = vr[q][m]; im[pos * 32 + c] = vi[q][m];
    }
  __syncthreads();

  const f32x2* xv = (const f32x2*)x;
  f32x2* ov = (f32x2*)out;
#pragma unroll
  for (int half = 0; half < 2; ++half) {
    const int g = 8 * half + p;
    float wr8[8], wi8[8];
#pragma unroll
    for (int j = 0; j < 8; ++j) { wr8[j] = re[(8 * g + j) * 32 + c]; wi8[j] = im[(8 * g + j) * 32 + c]; }
    bf4reg<false>(wr8[0], wi8[0], wr8[2], wi8[2], wr8[4], wi8[4], wr8[6], wi8[6],
                  1.f, 0.f, 1.f, 0.f, 1.f, 0.f);
    bf4reg<false>(wr8[1], wi8[1], wr8[3], wi8[3], wr8[5], wi8[5], wr8[7], wi8[7],
                  twr[16], -twi[16], twr[32], -twi[32], twr[48], -twi[48]);
#pragma unroll
    for (int j = 0; j < 8; j += 2) {
      const float ar = wr8[j], ai = wi8[j], br = wr8[j + 1], bi = wi8[j + 1];
      wr8[j] = ar + br; wi8[j] = ai + bi;
      wr8[j + 1] = ar - br; wi8[j + 1] = ai - bi;
    }
#pragma unroll
    for (int j = 0; j < 8; ++j) {
      const int w = drevinv(8 * g + j);
      const size_t fi = (size_t)bh * 49152 + w * 384 + (d0 >> 1) + c;
      const f32x2 s = __builtin_nontemporal_load(&xv[fi]);
      f32x2 o; o.x = wr8[j] + s.x; o.y = wi8[j] + s.y;
      __builtin_nontemporal_store(o, &ov[fi]);
    }
  }
}

// ---------------------------------------------------------------------------
extern "C" void kernel_launch(void* const* d_in, const int* in_sizes, int n_in,
                              void* d_out, int out_size, void* d_ws, size_t ws_size,
                              hipStream_t stream) {
  const float* x   = (const float*)d_in[0];
  const float* w1r = (const float*)d_in[1];
  const float* w1i = (const float*)d_in[2];
  const float* b1  = (const float*)d_in[3];
  const float* w2r = (const float*)d_in[4];
  const float* w2i = (const float*)d_in[5];
  const float* b2  = (const float*)d_in[6];
  unsigned* fq = (unsigned*)d_ws;
  float* out = (float*)d_out;

  const size_t need = (size_t)BH_ * FW * 768 * 4;  // 102,236,160 B
  if (ws_size < need) {
    fprintf(stderr, "kernel_launch: ws too small (%zu < %zu)\n", ws_size, need);
    return;
  }

  // packed bf16 weights at start of d_out (fully overwritten by k_inv_w later)
  unsigned short* wp = (unsigned short*)d_out;

  k_wpack<<<dim3(288), TPB, 0, stream>>>(w1r, w1i, w2r, w2i, wp);
  k_fwd_w<<<dim3(BH_, 12), TPB, 0, stream>>>(x, fq);
  k_fwd_h<<<dim3(B_, FW, 24), TPB, 0, stream>>>(fq);
  k_mlp_mfma<<<dim3(4160), TPB, 0, stream>>>(fq, (const bf16x8*)wp, b1, b2);
  k_inv_h<<<dim3(B_, FW, 24), TPB, 0, stream>>>(fq);
  k_inv_w<<<dim3(BH_, 12), TPB, 0, stream>>>(fq, x, out);
}

// Round 11
// 295.984 us; speedup vs baseline: 1.3811x; 1.0471x over previous
//
#include <hip/hip_runtime.h>
#include <hip/hip_bf16.h>
#include <cstdio>

#define TPB 256
#define B_ 4
#define H_ 128
#define W_ 128
#define D_ 768
#define FW 65
#define BH_ 512                  // B_*H_
#define THRESH_ 0.01f
#define NEG_TWO_PI_OVER_128 (-0.04908738521234052f)

typedef short bf16x8 __attribute__((ext_vector_type(8)));
typedef float f32x4 __attribute__((ext_vector_type(4)));
typedef float f32x2 __attribute__((ext_vector_type(2)));

// d_ws layout: fq  = u32[512*65*768]  (102,236,160 B)  -- pipeline buffer
//              fq2 = u32[512*65*768]  (102,236,160 B)  -- X checkpoint (skip)
// one u32 = packed (bf16 re, bf16 im); index ((bh)*65 + fw)*768 + d
// Mixed-radix 128 = 4*4*4*2 DIF; drev NOT involution; inverse drevinv.

__device__ __forceinline__ unsigned pk(float lo, float hi) {
  __hip_bfloat162 h2 = __float22bfloat162_rn(make_float2(lo, hi));
  return *(unsigned*)&h2;
}
__device__ __forceinline__ float2 upk(unsigned u) {
  return __bfloat1622float2(*(__hip_bfloat162*)&u);
}
__device__ __forceinline__ int drev(int k) {
  return ((k & 3) << 5) | (((k >> 2) & 3) << 3) | (((k >> 4) & 3) << 1) | ((k >> 6) & 1);
}
__device__ __forceinline__ int drevinv(int s) {
  return ((s & 1) << 6) | (((s >> 1) & 3) << 4) | (((s >> 3) & 3) << 2) | ((s >> 5) & 3);
}

template <bool FWD>
__device__ __forceinline__ void bf4reg(float& x0r, float& x0i, float& x1r, float& x1i,
                                       float& x2r, float& x2i, float& x3r, float& x3i,
                                       float c1, float s1, float c2, float s2, float c3, float s3) {
  const float v0r = x0r + x2r, v0i = x0i + x2i, v2r = x0r - x2r, v2i = x0i - x2i;
  const float v1r = x1r + x3r, v1i = x1i + x3i, v3r = x1r - x3r, v3i = x1i - x3i;
  float u1r, u1i, u3r, u3i;
  if (FWD) { u1r = v2r + v3i; u1i = v2i - v3r; u3r = v2r - v3i; u3i = v2i + v3r; }
  else     { u1r = v2r - v3i; u1i = v2i + v3r; u3r = v2r + v3i; u3i = v2i - v3r; }
  const float u2r = v0r - v1r, u2i = v0i - v1i;
  x0r = v0r + v1r;            x0i = v0i + v1i;
  x1r = u1r * c1 - u1i * s1;  x1i = u1r * s1 + u1i * c1;
  x2r = u2r * c2 - u2i * s2;  x2i = u2r * s2 + u2i * c2;
  x3r = u3r * c3 - u3i * s3;  x3i = u3r * s3 + u3i * c3;
}

__device__ __forceinline__ void ibf4r(float& x0r, float& x0i, float& x1r, float& x1i,
                                      float& x2r, float& x2i, float& x3r, float& x3i,
                                      float c1, float s1, float c2, float s2, float c3, float s3) {
  const float t0r = x0r, t0i = x0i;
  const float t1r = x1r * c1 + x1i * s1, t1i = x1i * c1 - x1r * s1;
  const float t2r = x2r * c2 + x2i * s2, t2i = x2i * c2 - x2r * s2;
  const float t3r = x3r * c3 + x3i * s3, t3i = x3i * c3 - x3r * s3;
  const float w0r = t0r + t2r, w0i = t0i + t2i, w2r = t0r - t2r, w2i = t0i - t2i;
  const float w1r = t1r + t3r, w1i = t1i + t3i, w3r = t1r - t3r, w3i = t1i - t3i;
  x0r = w0r + w1r; x0i = w0i + w1i;
  x1r = w2r - w3i; x1i = w2i + w3r;
  x2r = w0r - w1r; x2i = w0i - w1i;
  x3r = w2r + w3i; x3i = w2i - w3r;
}

#define TW_INIT() do { if (t < 128) { float s_, c_; \
    __sincosf(NEG_TWO_PI_OVER_128 * (float)t, &s_, &c_); twr[t] = c_; twi[t] = s_; } } while (0)

// ---------------------------------------------------------------------------
// K0: pack complex weights into bf16 B-fragment order (block form Wc).
// ---------------------------------------------------------------------------
__global__ __launch_bounds__(TPB) void k_wpack(const float* __restrict__ w1r,
                                               const float* __restrict__ w1i,
                                               const float* __restrict__ w2r,
                                               const float* __restrict__ w2i,
                                               unsigned short* __restrict__ wp) {
  const int tid = blockIdx.x * TPB + threadIdx.x;
  if (tid >= 2 * 36864) return;
  const int L = tid / 36864, rem = tid % 36864;
  const int n = rem / 192, k = rem % 192;
  const int c = k >> 1, s = k & 1, o = n >> 1, t = n & 1;
  const float* wr = L ? w2r : w1r;
  const float* wi = L ? w2i : w1i;
  const float val = (s == 0) ? (t == 0 ? wr[o * 96 + c] : wi[o * 96 + c])
                             : (t == 0 ? -wi[o * 96 + c] : wr[o * 96 + c]);
  __hip_bfloat16 h = __float2bfloat16(val);
  const int idx = ((n * 6 + (k >> 5)) * 4 + ((k >> 3) & 3)) * 8 + (k & 7);
  wp[L * 36864 + idx] = *(unsigned short*)&h;
}

// ---------------------------------------------------------------------------
// K1: forward rFFT over W via real-pair packing, two-phase register fusion.
// Writes X spectrum to BOTH fq (pipeline) and fq2 (skip checkpoint).
// x loads nontemporal. grid (512, 12).
// ---------------------------------------------------------------------------
__global__ __launch_bounds__(TPB) void k_fwd_w(const float* __restrict__ x,
                                               unsigned* __restrict__ fq,
                                               unsigned* __restrict__ fq2) {
  __shared__ float re[4096], im[4096], twr[128], twi[128];
  const int t = threadIdx.x;
  const int bh = blockIdx.x;
  const int d0 = blockIdx.y << 6;
  TW_INIT();
  const int c = t & 31, p = t >> 5;
  const f32x2* xp = (const f32x2*)(x + (size_t)bh * 98304 + d0);

  float vr[4][4], vi[4][4];
#pragma unroll
  for (int q = 0; q < 4; ++q)
#pragma unroll
    for (int m = 0; m < 4; ++m) {
      const f32x2 v = __builtin_nontemporal_load(&xp[(p + 8 * m + 32 * q) * 384 + c]);
      vr[q][m] = v.x; vi[q][m] = v.y;
    }
  __syncthreads();
#pragma unroll
  for (int m = 0; m < 4; ++m) {
    const int np = p + 8 * m;
    bf4reg<true>(vr[0][m], vi[0][m], vr[1][m], vi[1][m], vr[2][m], vi[2][m], vr[3][m], vi[3][m],
                 twr[np], twi[np], twr[2 * np], twi[2 * np], twr[3 * np], twi[3 * np]);
  }
#pragma unroll
  for (int q = 0; q < 4; ++q)
    bf4reg<true>(vr[q][0], vi[q][0], vr[q][1], vi[q][1], vr[q][2], vi[q][2], vr[q][3], vi[q][3],
                 twr[4 * p], twi[4 * p], twr[8 * p], twi[8 * p], twr[12 * p], twi[12 * p]);
#pragma unroll
  for (int q = 0; q < 4; ++q)
#pragma unroll
    for (int m = 0; m < 4; ++m) {
      const int pos = p + 8 * m + 32 * q;
      re[pos * 32 + c] = vr[q][m]; im[pos * 32 + c] = vi[q][m];
    }
  __syncthreads();

#pragma unroll
  for (int half = 0; half < 2; ++half) {
    const int g = 8 * half + p;
    float wr8[8], wi8[8];
#pragma unroll
    for (int j = 0; j < 8; ++j) { wr8[j] = re[(8 * g + j) * 32 + c]; wi8[j] = im[(8 * g + j) * 32 + c]; }
    bf4reg<true>(wr8[0], wi8[0], wr8[2], wi8[2], wr8[4], wi8[4], wr8[6], wi8[6],
                 1.f, 0.f, 1.f, 0.f, 1.f, 0.f);
    bf4reg<true>(wr8[1], wi8[1], wr8[3], wi8[3], wr8[5], wi8[5], wr8[7], wi8[7],
                 twr[16], twi[16], twr[32], twi[32], twr[48], twi[48]);
#pragma unroll
    for (int j = 0; j < 8; j += 2) {
      const float ar = wr8[j], ai = wi8[j], br = wr8[j + 1], bi = wi8[j + 1];
      wr8[j] = ar + br; wi8[j] = ai + bi;
      wr8[j + 1] = ar - br; wi8[j + 1] = ai - bi;
    }
#pragma unroll
    for (int j = 0; j < 8; ++j) {
      re[(8 * g + j) * 32 + c] = wr8[j]; im[(8 * g + j) * 32 + c] = wi8[j];
    }
  }
  __syncthreads();

#pragma unroll
  for (int it = 0; it < 9; ++it) {
    const int idx = it * TPB + t;
    if (idx < FW * 32) {
      const int q = idx >> 5, cc = idx & 31;
      const int sq = drev(q), smm = drev((128 - q) & 127);
      const float a = re[sq * 32 + cc], b = im[sq * 32 + cc];
      const float cr = re[smm * 32 + cc], dr = -im[smm * 32 + cc];
      const float hsc = 0.00390625f;  // 0.5 * (1/128)
      const float xer = (a + cr) * hsc, xei = (b + dr) * hsc;
      const float xor_ = (b - dr) * hsc, xoi = (cr - a) * hsc;
      const uint2 u = make_uint2(pk(xer, xei), pk(xor_, xoi));
      const size_t off = (size_t)(bh * FW + q) * 768 + d0 + 2 * cc;
      *(uint2*)(fq + off) = u;
      *(uint2*)(fq2 + off) = u;
    }
  }
}

// ---------------------------------------------------------------------------
// K2a: forward complex FFT over H, in-place; output digit-reversed slots.
// Two-stage register fusion. grid (4, 65, 24).
// ---------------------------------------------------------------------------
__global__ __launch_bounds__(TPB) void k_fwd_h(unsigned* __restrict__ fq) {
  __shared__ float re[4096], im[4096], twr[128], twi[128];
  const int t = threadIdx.x;
  const int b = blockIdx.x, fw = blockIdx.y, d0 = blockIdx.z << 5;
  TW_INIT();
  unsigned* fp = fq + (size_t)(b * 128 * FW + fw) * 768 + d0;
  const int c = t & 31, p = t >> 5;
  const size_t hs = (size_t)FW * 768;

  float vr[4][4], vi[4][4];
#pragma unroll
  for (int q = 0; q < 4; ++q)
#pragma unroll
    for (int m = 0; m < 4; ++m) {
      const float2 v = upk(fp[(size_t)(p + 8 * m + 32 * q) * hs + c]);
      vr[q][m] = v.x; vi[q][m] = v.y;
    }
  __syncthreads();
#pragma unroll
  for (int m = 0; m < 4; ++m) {
    const int np = p + 8 * m;
    bf4reg<true>(vr[0][m], vi[0][m], vr[1][m], vi[1][m], vr[2][m], vi[2][m], vr[3][m], vi[3][m],
                 twr[np], twi[np], twr[2 * np], twi[2 * np], twr[3 * np], twi[3 * np]);
  }
#pragma unroll
  for (int q = 0; q < 4; ++q)
    bf4reg<true>(vr[q][0], vi[q][0], vr[q][1], vi[q][1], vr[q][2], vi[q][2], vr[q][3], vi[q][3],
                 twr[4 * p], twi[4 * p], twr[8 * p], twi[8 * p], twr[12 * p], twi[12 * p]);
#pragma unroll
  for (int q = 0; q < 4; ++q)
#pragma unroll
    for (int m = 0; m < 4; ++m) {
      const int pos = p + 8 * m + 32 * q;
      re[pos * 32 + c] = vr[q][m]; im[pos * 32 + c] = vi[q][m];
    }
  __syncthreads();

#pragma unroll
  for (int half = 0; half < 2; ++half) {
    const int g = 8 * half + p;
    float wr8[8], wi8[8];
#pragma unroll
    for (int j = 0; j < 8; ++j) { wr8[j] = re[(8 * g + j) * 32 + c]; wi8[j] = im[(8 * g + j) * 32 + c]; }
    bf4reg<true>(wr8[0], wi8[0], wr8[2], wi8[2], wr8[4], wi8[4], wr8[6], wi8[6],
                 1.f, 0.f, 1.f, 0.f, 1.f, 0.f);
    bf4reg<true>(wr8[1], wi8[1], wr8[3], wi8[3], wr8[5], wi8[5], wr8[7], wi8[7],
                 twr[16], twi[16], twr[32], twi[32], twr[48], twi[48]);
#pragma unroll
    for (int j = 0; j < 8; j += 2) {
      const float ar = wr8[j], ai = wi8[j], br = wr8[j + 1], bi = wi8[j + 1];
      wr8[j] = ar + br; wi8[j] = ai + bi;
      wr8[j + 1] = ar - br; wi8[j + 1] = ai - bi;
    }
#pragma unroll
    for (int j = 0; j < 8; ++j)
      fp[(size_t)(8 * g + j) * hs + c] = pk(wr8[j], wi8[j]);
  }
}

// ---------------------------------------------------------------------------
// K2b: MFMA MLP, in-place on bf16 fq. M-tile 64 (24 KB LDS).
// ---------------------------------------------------------------------------
__global__ __launch_bounds__(TPB, 4) void k_mlp_mfma(unsigned* __restrict__ fq,
    const bf16x8* __restrict__ wpb,
    const float* __restrict__ b1, const float* __restrict__ b2) {
  __shared__ __align__(16) char lds[24576];   // 64 rows * 384 B
  const int t  = threadIdx.x;
  const int wv = t >> 6;
  const int l  = t & 63;
  const int c16 = l & 15, g = l >> 4, low3 = l & 7;
  const int n0 = wv * 48;
  const int P0 = blockIdx.x << 6;

  const uint4* src = (const uint4*)(fq + (size_t)P0 * 96);
#pragma unroll
  for (int it = 0; it < 6; ++it) {
    const int q = it * TPB + t;                 // 1536 uint4s
    const int row = q / 24, f = q % 24;
    *(uint4*)(lds + row * 384 + ((f * 16) ^ ((row & 7) << 4))) = src[q];
  }
  __syncthreads();

  f32x4 acc[4][3];
  float bs0 = b1[n0 + c16], bs1 = b1[n0 + 16 + c16], bs2 = b1[n0 + 32 + c16];

#pragma unroll
  for (int mt = 0; mt < 4; ++mt)
#pragma unroll
    for (int np = 0; np < 3; ++np) acc[mt][np] = (f32x4)0.f;
  for (int kk = 0; kk < 6; ++kk) {
    bf16x8 a[4];
#pragma unroll
    for (int mt = 0; mt < 4; ++mt) {
      const int row = (mt << 4) + c16;
      a[mt] = *(const bf16x8*)(lds + row * 384 + ((kk * 64 + g * 16) ^ (low3 << 4)));
    }
    bf16x8 bfr[3];
#pragma unroll
    for (int np = 0; np < 3; ++np) bfr[np] = wpb[((n0 + np * 16 + c16) * 6 + kk) * 4 + g];
#pragma unroll
    for (int mt = 0; mt < 4; ++mt)
#pragma unroll
      for (int np = 0; np < 3; ++np)
        acc[mt][np] = __builtin_amdgcn_mfma_f32_16x16x32_bf16(a[mt], bfr[np], acc[mt][np], 0, 0, 0);
  }
  __syncthreads();
#pragma unroll
  for (int mt = 0; mt < 4; ++mt)
#pragma unroll
    for (int np = 0; np < 3; ++np) {
      const int col = n0 + np * 16 + c16;
      const float bb = np == 0 ? bs0 : (np == 1 ? bs1 : bs2);
#pragma unroll
      for (int r = 0; r < 4; ++r) {
        const int row = (mt << 4) + (g << 2) + r;
        const float vv = fmaxf(acc[mt][np][r] + bb, 0.f);
        __hip_bfloat16 hb = __float2bfloat16(vv);
        *(unsigned short*)(lds + row * 384 + ((2 * col) ^ ((row & 7) << 4))) = *(unsigned short*)&hb;
      }
    }
  __syncthreads();

  bs0 = b2[n0 + c16]; bs1 = b2[n0 + 16 + c16]; bs2 = b2[n0 + 32 + c16];
#pragma unroll
  for (int mt = 0; mt < 4; ++mt)
#pragma unroll
    for (int np = 0; np < 3; ++np) acc[mt][np] = (f32x4)0.f;
  const bf16x8* wpb2 = wpb + 4608;
  for (int kk = 0; kk < 6; ++kk) {
    bf16x8 a[4];
#pragma unroll
    for (int mt = 0; mt < 4; ++mt) {
      const int row = (mt << 4) + c16;
      a[mt] = *(const bf16x8*)(lds + row * 384 + ((kk * 64 + g * 16) ^ (low3 << 4)));
    }
    bf16x8 bfr[3];
#pragma unroll
    for (int np = 0; np < 3; ++np) bfr[np] = wpb2[((n0 + np * 16 + c16) * 6 + kk) * 4 + g];
#pragma unroll
    for (int mt = 0; mt < 4; ++mt)
#pragma unroll
      for (int np = 0; np < 3; ++np)
        acc[mt][np] = __builtin_amdgcn_mfma_f32_16x16x32_bf16(a[mt], bfr[np], acc[mt][np], 0, 0, 0);
  }
  unsigned short* fq16 = (unsigned short*)fq;
#pragma unroll
  for (int mt = 0; mt < 4; ++mt)
#pragma unroll
    for (int np = 0; np < 3; ++np) {
      const int col = n0 + np * 16 + c16;
      const float bb = np == 0 ? bs0 : (np == 1 ? bs1 : bs2);
#pragma unroll
      for (int r = 0; r < 4; ++r) {
        const int row = (mt << 4) + (g << 2) + r;
        float vv = acc[mt][np][r] + bb;
        vv = (vv > THRESH_) ? (vv - THRESH_) : ((vv < -THRESH_) ? (vv + THRESH_) : 0.f);
        __hip_bfloat16 hb = __float2bfloat16(vv);
        fq16[(size_t)(P0 + row) * 192 + col] = *(unsigned short*)&hb;
      }
    }
}

// ---------------------------------------------------------------------------
// K2c: inverse FFT over H (DIT, digit-reversed in, natural out, e^+i),
// two-stage register fusion. In-place bf16. grid (4, 65, 24).
// ---------------------------------------------------------------------------
__global__ __launch_bounds__(TPB) void k_inv_h(unsigned* __restrict__ fq) {
  __shared__ float re[4096], im[4096], twr[128], twi[128];
  const int t = threadIdx.x;
  const int b = blockIdx.x, fw = blockIdx.y, d0 = blockIdx.z << 5;
  TW_INIT();
  unsigned* fp = fq + (size_t)(b * 128 * FW + fw) * 768 + d0;
  const int c = t & 31, p = t >> 5;
  const size_t hs = (size_t)FW * 768;

#pragma unroll
  for (int half = 0; half < 2; ++half) {
    const int g = 8 * half + p;
    float wr8[8], wi8[8];
#pragma unroll
    for (int j = 0; j < 8; ++j) {
      const float2 v = upk(fp[(size_t)(8 * g + j) * hs + c]);
      wr8[j] = v.x; wi8[j] = v.y;
    }
    if (half == 0) __syncthreads();  // twiddle table ready (once)
#pragma unroll
    for (int j = 0; j < 8; j += 2) {
      const float ar = wr8[j], ai = wi8[j], br = wr8[j + 1], bi = wi8[j + 1];
      wr8[j] = ar + br; wi8[j] = ai + bi;
      wr8[j + 1] = ar - br; wi8[j + 1] = ai - bi;
    }
    ibf4r(wr8[0], wi8[0], wr8[2], wi8[2], wr8[4], wi8[4], wr8[6], wi8[6],
          1.f, 0.f, 1.f, 0.f, 1.f, 0.f);
    ibf4r(wr8[1], wi8[1], wr8[3], wi8[3], wr8[5], wi8[5], wr8[7], wi8[7],
          twr[16], twi[16], twr[32], twi[32], twr[48], twi[48]);
#pragma unroll
    for (int j = 0; j < 8; ++j) {
      re[(8 * g + j) * 32 + c] = wr8[j]; im[(8 * g + j) * 32 + c] = wi8[j];
    }
  }
  __syncthreads();

  float vr[4][4], vi[4][4];
#pragma unroll
  for (int q = 0; q < 4; ++q)
#pragma unroll
    for (int m = 0; m < 4; ++m) {
      const int pos = p + 8 * m + 32 * q;
      vr[q][m] = re[pos * 32 + c]; vi[q][m] = im[pos * 32 + c];
    }
#pragma unroll
  for (int q = 0; q < 4; ++q)
    ibf4r(vr[q][0], vi[q][0], vr[q][1], vi[q][1], vr[q][2], vi[q][2], vr[q][3], vi[q][3],
          twr[4 * p], twi[4 * p], twr[8 * p], twi[8 * p], twr[12 * p], twi[12 * p]);
#pragma unroll
  for (int m = 0; m < 4; ++m) {
    const int np = p + 8 * m;
    ibf4r(vr[0][m], vi[0][m], vr[1][m], vi[1][m], vr[2][m], vi[2][m], vr[3][m], vi[3][m],
          twr[np], twi[np], twr[2 * np], twi[2 * np], twr[3 * np], twi[3 * np]);
  }
#pragma unroll
  for (int q = 0; q < 4; ++q)
#pragma unroll
    for (int m = 0; m < 4; ++m)
      fp[(size_t)(p + 8 * m + 32 * q) * hs + c] = pk(vr[q][m], vi[q][m]);
}

// ---------------------------------------------------------------------------
// K3: inverse rFFT over W with frequency-domain skip: Z = Y*sc + X (X from
// fq2, unscaled). Direct nt store. grid (512, 12).
// ---------------------------------------------------------------------------
__global__ __launch_bounds__(TPB) void k_inv_w(const unsigned* __restrict__ fq,
                                               const unsigned* __restrict__ fq2,
                                               float* __restrict__ out) {
  __shared__ float re[4096], im[4096], twr[128], twi[128];
  const int t = threadIdx.x;
  const int bh = blockIdx.x;
  const int d0 = blockIdx.y << 6;
  TW_INIT();
  const int c = t & 31, p = t >> 5;
  const float sc = 0.0078125f;  // 1/128 (on Y only; X enters unscaled)

#pragma unroll
  for (int it = 0; it < 9; ++it) {
    const int idx = it * TPB + t;
    if (idx < FW * 32) {
      const int q = idx >> 5, cc = idx & 31;
      const size_t off = (size_t)(bh * FW + q) * 768 + d0 + 2 * cc;
      const uint2 vv = *(const uint2*)(fq + off);
      const uint2 xx = *(const uint2*)(fq2 + off);
      const float2 e = upk(vv.x), o = upk(vv.y);
      const float2 e2 = upk(xx.x), o2 = upk(xx.y);
      const float zer = e.x * sc + e2.x, zei = e.y * sc + e2.y;
      const float zor = o.x * sc + o2.x, zoi = o.y * sc + o2.y;
      re[q * 32 + cc] = zer - zoi; im[q * 32 + cc] = zei + zor;
      if (q >= 1 && q <= 63) {
        re[(128 - q) * 32 + cc] = zer + zoi;
        im[(128 - q) * 32 + cc] = zor - zei;
      }
    }
  }
  __syncthreads();

  float vr[4][4], vi[4][4];
#pragma unroll
  for (int q = 0; q < 4; ++q)
#pragma unroll
    for (int m = 0; m < 4; ++m) {
      const int pos = p + 8 * m + 32 * q;
      vr[q][m] = re[pos * 32 + c]; vi[q][m] = im[pos * 32 + c];
    }
#pragma unroll
  for (int m = 0; m < 4; ++m) {
    const int np = p + 8 * m;
    bf4reg<false>(vr[0][m], vi[0][m], vr[1][m], vi[1][m], vr[2][m], vi[2][m], vr[3][m], vi[3][m],
                  twr[np], -twi[np], twr[2 * np], -twi[2 * np], twr[3 * np], -twi[3 * np]);
  }
#pragma unroll
  for (int q = 0; q < 4; ++q)
    bf4reg<false>(vr[q][0], vi[q][0], vr[q][1], vi[q][1], vr[q][2], vi[q][2], vr[q][3], vi[q][3],
                  twr[4 * p], -twi[4 * p], twr[8 * p], -twi[8 * p], twr[12 * p], -twi[12 * p]);
#pragma unroll
  for (int q = 0; q < 4; ++q)
#pragma unroll
    for (int m = 0; m < 4; ++m) {
      const int pos = p + 8 * m + 32 * q;
      re[pos * 32 + c] = vr[q][m]; im[pos * 32 + c] = vi[q][m];
    }
  __syncthreads();

  f32x2* ov = (f32x2*)out;
#pragma unroll
  for (int half = 0; half < 2; ++half) {
    const int g = 8 * half + p;
    float wr8[8], wi8[8];
#pragma unroll
    for (int j = 0; j < 8; ++j) { wr8[j] = re[(8 * g + j) * 32 + c]; wi8[j] = im[(8 * g + j) * 32 + c]; }
    bf4reg<false>(wr8[0], wi8[0], wr8[2], wi8[2], wr8[4], wi8[4], wr8[6], wi8[6],
                  1.f, 0.f, 1.f, 0.f, 1.f, 0.f);
    bf4reg<false>(wr8[1], wi8[1], wr8[3], wi8[3], wr8[5], wi8[5], wr8[7], wi8[7],
                  twr[16], -twi[16], twr[32], -twi[32], twr[48], -twi[48]);
#pragma unroll
    for (int j = 0; j < 8; j += 2) {
      const float ar = wr8[j], ai = wi8[j], br = wr8[j + 1], bi = wi8[j + 1];
      wr8[j] = ar + br; wi8[j] = ai + bi;
      wr8[j + 1] = ar - br; wi8[j + 1] = ai - bi;
    }
#pragma unroll
    for (int j = 0; j < 8; ++j) {
      const int w = drevinv(8 * g + j);
      const size_t fi = (size_t)bh * 49152 + w * 384 + (d0 >> 1) + c;
      f32x2 o; o.x = wr8[j]; o.y = wi8[j];
      __builtin_nontemporal_store(o, &ov[fi]);
    }
  }
}

// ---------------------------------------------------------------------------
extern "C" void kernel_launch(void* const* d_in, const int* in_sizes, int n_in,
                              void* d_out, int out_size, void* d_ws, size_t ws_size,
                              hipStream_t stream) {
  const float* x   = (const float*)d_in[0];
  const float* w1r = (const float*)d_in[1];
  const float* w1i = (const float*)d_in[2];
  const float* b1  = (const float*)d_in[3];
  const float* w2r = (const float*)d_in[4];
  const float* w2i = (const float*)d_in[5];
  const float* b2  = (const float*)d_in[6];
  unsigned* fq  = (unsigned*)d_ws;
  unsigned* fq2 = fq + (size_t)BH_ * FW * 768;   // second 102 MB region
  float* out = (float*)d_out;

  const size_t need = (size_t)BH_ * FW * 768 * 4 * 2;  // 204,472,320 B
  if (ws_size < need) {
    fprintf(stderr, "kernel_launch: ws too small (%zu < %zu)\n", ws_size, need);
    return;
  }

  // packed bf16 weights at start of d_out (fully overwritten by k_inv_w later)
  unsigned short* wp = (unsigned short*)d_out;

  k_wpack<<<dim3(288), TPB, 0, stream>>>(w1r, w1i, w2r, w2i, wp);
  k_fwd_w<<<dim3(BH_, 12), TPB, 0, stream>>>(x, fq, fq2);
  k_fwd_h<<<dim3(B_, FW, 24), TPB, 0, stream>>>(fq);
  k_mlp_mfma<<<dim3(4160), TPB, 0, stream>>>(fq, (const bf16x8*)wp, b1, b2);
  k_inv_h<<<dim3(B_, FW, 24), TPB, 0, stream>>>(fq);
  k_inv_w<<<dim3(BH_, 12), TPB, 0, stream>>>(fq, fq2, out);
}

// Round 12
// 285.499 us; speedup vs baseline: 1.4318x; 1.0367x over previous
//
#include <hip/hip_runtime.h>
#include <hip/hip_bf16.h>
#include <cstdio>

#define TPB 256
#define B_ 4
#define H_ 128
#define W_ 128
#define D_ 768
#define FW 65
#define BH_ 512                  // B_*H_
#define THRESH_ 0.01f
#define NEG_TWO_PI_OVER_128 (-0.04908738521234052f)

typedef short bf16x8 __attribute__((ext_vector_type(8)));
typedef float f32x4 __attribute__((ext_vector_type(4)));
typedef float f32x2 __attribute__((ext_vector_type(2)));

// d_ws layout: fq  = u32[512*65*768] -- X checkpoint (written once by fwd_w,
//                                       read by fwd_h and inv_w; never touched
//                                       by the mid pipeline)
//              fq2 = u32[512*65*768] -- pipeline buffer (fwd_h out, mlp/inv_h
//                                       in-place, inv_w Y input)
// one u32 = packed (bf16 re, bf16 im); index ((bh)*65 + fw)*768 + d
// Mixed-radix 128 = 4*4*4*2 DIF; drev NOT involution; inverse drevinv.

__device__ __forceinline__ unsigned pk(float lo, float hi) {
  __hip_bfloat162 h2 = __float22bfloat162_rn(make_float2(lo, hi));
  return *(unsigned*)&h2;
}
__device__ __forceinline__ float2 upk(unsigned u) {
  return __bfloat1622float2(*(__hip_bfloat162*)&u);
}
__device__ __forceinline__ int drev(int k) {
  return ((k & 3) << 5) | (((k >> 2) & 3) << 3) | (((k >> 4) & 3) << 1) | ((k >> 6) & 1);
}
__device__ __forceinline__ int drevinv(int s) {
  return ((s & 1) << 6) | (((s >> 1) & 3) << 4) | (((s >> 3) & 3) << 2) | ((s >> 5) & 3);
}

template <bool FWD>
__device__ __forceinline__ void bf4reg(float& x0r, float& x0i, float& x1r, float& x1i,
                                       float& x2r, float& x2i, float& x3r, float& x3i,
                                       float c1, float s1, float c2, float s2, float c3, float s3) {
  const float v0r = x0r + x2r, v0i = x0i + x2i, v2r = x0r - x2r, v2i = x0i - x2i;
  const float v1r = x1r + x3r, v1i = x1i + x3i, v3r = x1r - x3r, v3i = x1i - x3i;
  float u1r, u1i, u3r, u3i;
  if (FWD) { u1r = v2r + v3i; u1i = v2i - v3r; u3r = v2r - v3i; u3i = v2i + v3r; }
  else     { u1r = v2r - v3i; u1i = v2i + v3r; u3r = v2r + v3i; u3i = v2i - v3r; }
  const float u2r = v0r - v1r, u2i = v0i - v1i;
  x0r = v0r + v1r;            x0i = v0i + v1i;
  x1r = u1r * c1 - u1i * s1;  x1i = u1r * s1 + u1i * c1;
  x2r = u2r * c2 - u2i * s2;  x2i = u2r * s2 + u2i * c2;
  x3r = u3r * c3 - u3i * s3;  x3i = u3r * s3 + u3i * c3;
}

__device__ __forceinline__ void ibf4r(float& x0r, float& x0i, float& x1r, float& x1i,
                                      float& x2r, float& x2i, float& x3r, float& x3i,
                                      float c1, float s1, float c2, float s2, float c3, float s3) {
  const float t0r = x0r, t0i = x0i;
  const float t1r = x1r * c1 + x1i * s1, t1i = x1i * c1 - x1r * s1;
  const float t2r = x2r * c2 + x2i * s2, t2i = x2i * c2 - x2r * s2;
  const float t3r = x3r * c3 + x3i * s3, t3i = x3i * c3 - x3r * s3;
  const float w0r = t0r + t2r, w0i = t0i + t2i, w2r = t0r - t2r, w2i = t0i - t2i;
  const float w1r = t1r + t3r, w1i = t1i + t3i, w3r = t1r - t3r, w3i = t1i - t3i;
  x0r = w0r + w1r; x0i = w0i + w1i;
  x1r = w2r - w3i; x1i = w2i + w3r;
  x2r = w0r - w1r; x2i = w0i - w1i;
  x3r = w2r + w3i; x3i = w2i - w3r;
}

#define TW_INIT() do { if (t < 128) { float s_, c_; \
    __sincosf(NEG_TWO_PI_OVER_128 * (float)t, &s_, &c_); twr[t] = c_; twi[t] = s_; } } while (0)

// ---------------------------------------------------------------------------
// K0: pack complex weights into bf16 B-fragment order (block form Wc).
// ---------------------------------------------------------------------------
__global__ __launch_bounds__(TPB) void k_wpack(const float* __restrict__ w1r,
                                               const float* __restrict__ w1i,
                                               const float* __restrict__ w2r,
                                               const float* __restrict__ w2i,
                                               unsigned short* __restrict__ wp) {
  const int tid = blockIdx.x * TPB + threadIdx.x;
  if (tid >= 2 * 36864) return;
  const int L = tid / 36864, rem = tid % 36864;
  const int n = rem / 192, k = rem % 192;
  const int c = k >> 1, s = k & 1, o = n >> 1, t = n & 1;
  const float* wr = L ? w2r : w1r;
  const float* wi = L ? w2i : w1i;
  const float val = (s == 0) ? (t == 0 ? wr[o * 96 + c] : wi[o * 96 + c])
                             : (t == 0 ? -wi[o * 96 + c] : wr[o * 96 + c]);
  __hip_bfloat16 h = __float2bfloat16(val);
  const int idx = ((n * 6 + (k >> 5)) * 4 + ((k >> 3) & 3)) * 8 + (k & 7);
  wp[L * 36864 + idx] = *(unsigned short*)&h;
}

// ---------------------------------------------------------------------------
// K1: forward rFFT over W via real-pair packing, two-phase register fusion.
// Writes X spectrum ONCE to fq (checkpoint). x loads nt. grid (512, 12).
// ---------------------------------------------------------------------------
__global__ __launch_bounds__(TPB) void k_fwd_w(const float* __restrict__ x,
                                               unsigned* __restrict__ fq) {
  __shared__ float re[4096], im[4096], twr[128], twi[128];
  const int t = threadIdx.x;
  const int bh = blockIdx.x;
  const int d0 = blockIdx.y << 6;
  TW_INIT();
  const int c = t & 31, p = t >> 5;
  const f32x2* xp = (const f32x2*)(x + (size_t)bh * 98304 + d0);

  float vr[4][4], vi[4][4];
#pragma unroll
  for (int q = 0; q < 4; ++q)
#pragma unroll
    for (int m = 0; m < 4; ++m) {
      const f32x2 v = __builtin_nontemporal_load(&xp[(p + 8 * m + 32 * q) * 384 + c]);
      vr[q][m] = v.x; vi[q][m] = v.y;
    }
  __syncthreads();
#pragma unroll
  for (int m = 0; m < 4; ++m) {
    const int np = p + 8 * m;
    bf4reg<true>(vr[0][m], vi[0][m], vr[1][m], vi[1][m], vr[2][m], vi[2][m], vr[3][m], vi[3][m],
                 twr[np], twi[np], twr[2 * np], twi[2 * np], twr[3 * np], twi[3 * np]);
  }
#pragma unroll
  for (int q = 0; q < 4; ++q)
    bf4reg<true>(vr[q][0], vi[q][0], vr[q][1], vi[q][1], vr[q][2], vi[q][2], vr[q][3], vi[q][3],
                 twr[4 * p], twi[4 * p], twr[8 * p], twi[8 * p], twr[12 * p], twi[12 * p]);
#pragma unroll
  for (int q = 0; q < 4; ++q)
#pragma unroll
    for (int m = 0; m < 4; ++m) {
      const int pos = p + 8 * m + 32 * q;
      re[pos * 32 + c] = vr[q][m]; im[pos * 32 + c] = vi[q][m];
    }
  __syncthreads();

#pragma unroll
  for (int half = 0; half < 2; ++half) {
    const int g = 8 * half + p;
    float wr8[8], wi8[8];
#pragma unroll
    for (int j = 0; j < 8; ++j) { wr8[j] = re[(8 * g + j) * 32 + c]; wi8[j] = im[(8 * g + j) * 32 + c]; }
    bf4reg<true>(wr8[0], wi8[0], wr8[2], wi8[2], wr8[4], wi8[4], wr8[6], wi8[6],
                 1.f, 0.f, 1.f, 0.f, 1.f, 0.f);
    bf4reg<true>(wr8[1], wi8[1], wr8[3], wi8[3], wr8[5], wi8[5], wr8[7], wi8[7],
                 twr[16], twi[16], twr[32], twi[32], twr[48], twi[48]);
#pragma unroll
    for (int j = 0; j < 8; j += 2) {
      const float ar = wr8[j], ai = wi8[j], br = wr8[j + 1], bi = wi8[j + 1];
      wr8[j] = ar + br; wi8[j] = ai + bi;
      wr8[j + 1] = ar - br; wi8[j + 1] = ai - bi;
    }
#pragma unroll
    for (int j = 0; j < 8; ++j) {
      re[(8 * g + j) * 32 + c] = wr8[j]; im[(8 * g + j) * 32 + c] = wi8[j];
    }
  }
  __syncthreads();

#pragma unroll
  for (int it = 0; it < 9; ++it) {
    const int idx = it * TPB + t;
    if (idx < FW * 32) {
      const int q = idx >> 5, cc = idx & 31;
      const int sq = drev(q), smm = drev((128 - q) & 127);
      const float a = re[sq * 32 + cc], b = im[sq * 32 + cc];
      const float cr = re[smm * 32 + cc], dr = -im[smm * 32 + cc];
      const float hsc = 0.00390625f;  // 0.5 * (1/128)
      const float xer = (a + cr) * hsc, xei = (b + dr) * hsc;
      const float xor_ = (b - dr) * hsc, xoi = (cr - a) * hsc;
      *(uint2*)(fq + (size_t)(bh * FW + q) * 768 + d0 + 2 * cc) =
          make_uint2(pk(xer, xei), pk(xor_, xoi));
    }
  }
}

// ---------------------------------------------------------------------------
// K2a: forward complex FFT over H; reads fq (X checkpoint), writes fq2
// (digit-reversed slots). Two-stage register fusion. grid (4, 65, 24).
// ---------------------------------------------------------------------------
__global__ __launch_bounds__(TPB) void k_fwd_h(const unsigned* __restrict__ fq,
                                               unsigned* __restrict__ fq2) {
  __shared__ float re[4096], im[4096], twr[128], twi[128];
  const int t = threadIdx.x;
  const int b = blockIdx.x, fw = blockIdx.y, d0 = blockIdx.z << 5;
  TW_INIT();
  const size_t base = (size_t)(b * 128 * FW + fw) * 768 + d0;
  const unsigned* fin = fq + base;
  unsigned* fout = fq2 + base;
  const int c = t & 31, p = t >> 5;
  const size_t hs = (size_t)FW * 768;

  float vr[4][4], vi[4][4];
#pragma unroll
  for (int q = 0; q < 4; ++q)
#pragma unroll
    for (int m = 0; m < 4; ++m) {
      const float2 v = upk(fin[(size_t)(p + 8 * m + 32 * q) * hs + c]);
      vr[q][m] = v.x; vi[q][m] = v.y;
    }
  __syncthreads();
#pragma unroll
  for (int m = 0; m < 4; ++m) {
    const int np = p + 8 * m;
    bf4reg<true>(vr[0][m], vi[0][m], vr[1][m], vi[1][m], vr[2][m], vi[2][m], vr[3][m], vi[3][m],
                 twr[np], twi[np], twr[2 * np], twi[2 * np], twr[3 * np], twi[3 * np]);
  }
#pragma unroll
  for (int q = 0; q < 4; ++q)
    bf4reg<true>(vr[q][0], vi[q][0], vr[q][1], vi[q][1], vr[q][2], vi[q][2], vr[q][3], vi[q][3],
                 twr[4 * p], twi[4 * p], twr[8 * p], twi[8 * p], twr[12 * p], twi[12 * p]);
#pragma unroll
  for (int q = 0; q < 4; ++q)
#pragma unroll
    for (int m = 0; m < 4; ++m) {
      const int pos = p + 8 * m + 32 * q;
      re[pos * 32 + c] = vr[q][m]; im[pos * 32 + c] = vi[q][m];
    }
  __syncthreads();

#pragma unroll
  for (int half = 0; half < 2; ++half) {
    const int g = 8 * half + p;
    float wr8[8], wi8[8];
#pragma unroll
    for (int j = 0; j < 8; ++j) { wr8[j] = re[(8 * g + j) * 32 + c]; wi8[j] = im[(8 * g + j) * 32 + c]; }
    bf4reg<true>(wr8[0], wi8[0], wr8[2], wi8[2], wr8[4], wi8[4], wr8[6], wi8[6],
                 1.f, 0.f, 1.f, 0.f, 1.f, 0.f);
    bf4reg<true>(wr8[1], wi8[1], wr8[3], wi8[3], wr8[5], wi8[5], wr8[7], wi8[7],
                 twr[16], twi[16], twr[32], twi[32], twr[48], twi[48]);
#pragma unroll
    for (int j = 0; j < 8; j += 2) {
      const float ar = wr8[j], ai = wi8[j], br = wr8[j + 1], bi = wi8[j + 1];
      wr8[j] = ar + br; wi8[j] = ai + bi;
      wr8[j + 1] = ar - br; wi8[j + 1] = ai - bi;
    }
#pragma unroll
    for (int j = 0; j < 8; ++j)
      fout[(size_t)(8 * g + j) * hs + c] = pk(wr8[j], wi8[j]);
  }
}

// ---------------------------------------------------------------------------
// K2b: MFMA MLP, in-place on bf16 fq2. M-tile 64 (24 KB LDS).
// ---------------------------------------------------------------------------
__global__ __launch_bounds__(TPB, 4) void k_mlp_mfma(unsigned* __restrict__ fq2,
    const bf16x8* __restrict__ wpb,
    const float* __restrict__ b1, const float* __restrict__ b2) {
  __shared__ __align__(16) char lds[24576];   // 64 rows * 384 B
  const int t  = threadIdx.x;
  const int wv = t >> 6;
  const int l  = t & 63;
  const int c16 = l & 15, g = l >> 4, low3 = l & 7;
  const int n0 = wv * 48;
  const int P0 = blockIdx.x << 6;

  const uint4* src = (const uint4*)(fq2 + (size_t)P0 * 96);
#pragma unroll
  for (int it = 0; it < 6; ++it) {
    const int q = it * TPB + t;                 // 1536 uint4s
    const int row = q / 24, f = q % 24;
    *(uint4*)(lds + row * 384 + ((f * 16) ^ ((row & 7) << 4))) = src[q];
  }
  __syncthreads();

  f32x4 acc[4][3];
  float bs0 = b1[n0 + c16], bs1 = b1[n0 + 16 + c16], bs2 = b1[n0 + 32 + c16];

#pragma unroll
  for (int mt = 0; mt < 4; ++mt)
#pragma unroll
    for (int np = 0; np < 3; ++np) acc[mt][np] = (f32x4)0.f;
  for (int kk = 0; kk < 6; ++kk) {
    bf16x8 a[4];
#pragma unroll
    for (int mt = 0; mt < 4; ++mt) {
      const int row = (mt << 4) + c16;
      a[mt] = *(const bf16x8*)(lds + row * 384 + ((kk * 64 + g * 16) ^ (low3 << 4)));
    }
    bf16x8 bfr[3];
#pragma unroll
    for (int np = 0; np < 3; ++np) bfr[np] = wpb[((n0 + np * 16 + c16) * 6 + kk) * 4 + g];
#pragma unroll
    for (int mt = 0; mt < 4; ++mt)
#pragma unroll
      for (int np = 0; np < 3; ++np)
        acc[mt][np] = __builtin_amdgcn_mfma_f32_16x16x32_bf16(a[mt], bfr[np], acc[mt][np], 0, 0, 0);
  }
  __syncthreads();
#pragma unroll
  for (int mt = 0; mt < 4; ++mt)
#pragma unroll
    for (int np = 0; np < 3; ++np) {
      const int col = n0 + np * 16 + c16;
      const float bb = np == 0 ? bs0 : (np == 1 ? bs1 : bs2);
#pragma unroll
      for (int r = 0; r < 4; ++r) {
        const int row = (mt << 4) + (g << 2) + r;
        const float vv = fmaxf(acc[mt][np][r] + bb, 0.f);
        __hip_bfloat16 hb = __float2bfloat16(vv);
        *(unsigned short*)(lds + row * 384 + ((2 * col) ^ ((row & 7) << 4))) = *(unsigned short*)&hb;
      }
    }
  __syncthreads();

  bs0 = b2[n0 + c16]; bs1 = b2[n0 + 16 + c16]; bs2 = b2[n0 + 32 + c16];
#pragma unroll
  for (int mt = 0; mt < 4; ++mt)
#pragma unroll
    for (int np = 0; np < 3; ++np) acc[mt][np] = (f32x4)0.f;
  const bf16x8* wpb2 = wpb + 4608;
  for (int kk = 0; kk < 6; ++kk) {
    bf16x8 a[4];
#pragma unroll
    for (int mt = 0; mt < 4; ++mt) {
      const int row = (mt << 4) + c16;
      a[mt] = *(const bf16x8*)(lds + row * 384 + ((kk * 64 + g * 16) ^ (low3 << 4)));
    }
    bf16x8 bfr[3];
#pragma unroll
    for (int np = 0; np < 3; ++np) bfr[np] = wpb2[((n0 + np * 16 + c16) * 6 + kk) * 4 + g];
#pragma unroll
    for (int mt = 0; mt < 4; ++mt)
#pragma unroll
      for (int np = 0; np < 3; ++np)
        acc[mt][np] = __builtin_amdgcn_mfma_f32_16x16x32_bf16(a[mt], bfr[np], acc[mt][np], 0, 0, 0);
  }
  unsigned short* fq16 = (unsigned short*)fq2;
#pragma unroll
  for (int mt = 0; mt < 4; ++mt)
#pragma unroll
    for (int np = 0; np < 3; ++np) {
      const int col = n0 + np * 16 + c16;
      const float bb = np == 0 ? bs0 : (np == 1 ? bs1 : bs2);
#pragma unroll
      for (int r = 0; r < 4; ++r) {
        const int row = (mt << 4) + (g << 2) + r;
        float vv = acc[mt][np][r] + bb;
        vv = (vv > THRESH_) ? (vv - THRESH_) : ((vv < -THRESH_) ? (vv + THRESH_) : 0.f);
        __hip_bfloat16 hb = __float2bfloat16(vv);
        fq16[(size_t)(P0 + row) * 192 + col] = *(unsigned short*)&hb;
      }
    }
}

// ---------------------------------------------------------------------------
// K2c: inverse FFT over H (DIT, digit-reversed in, natural out, e^+i),
// two-stage register fusion. In-place on bf16 fq2. grid (4, 65, 24).
// ---------------------------------------------------------------------------
__global__ __launch_bounds__(TPB) void k_inv_h(unsigned* __restrict__ fq2) {
  __shared__ float re[4096], im[4096], twr[128], twi[128];
  const int t = threadIdx.x;
  const int b = blockIdx.x, fw = blockIdx.y, d0 = blockIdx.z << 5;
  TW_INIT();
  unsigned* fp = fq2 + (size_t)(b * 128 * FW + fw) * 768 + d0;
  const int c = t & 31, p = t >> 5;
  const size_t hs = (size_t)FW * 768;

#pragma unroll
  for (int half = 0; half < 2; ++half) {
    const int g = 8 * half + p;
    float wr8[8], wi8[8];
#pragma unroll
    for (int j = 0; j < 8; ++j) {
      const float2 v = upk(fp[(size_t)(8 * g + j) * hs + c]);
      wr8[j] = v.x; wi8[j] = v.y;
    }
    if (half == 0) __syncthreads();  // twiddle table ready (once)
#pragma unroll
    for (int j = 0; j < 8; j += 2) {
      const float ar = wr8[j], ai = wi8[j], br = wr8[j + 1], bi = wi8[j + 1];
      wr8[j] = ar + br; wi8[j] = ai + bi;
      wr8[j + 1] = ar - br; wi8[j + 1] = ai - bi;
    }
    ibf4r(wr8[0], wi8[0], wr8[2], wi8[2], wr8[4], wi8[4], wr8[6], wi8[6],
          1.f, 0.f, 1.f, 0.f, 1.f, 0.f);
    ibf4r(wr8[1], wi8[1], wr8[3], wi8[3], wr8[5], wi8[5], wr8[7], wi8[7],
          twr[16], twi[16], twr[32], twi[32], twr[48], twi[48]);
#pragma unroll
    for (int j = 0; j < 8; ++j) {
      re[(8 * g + j) * 32 + c] = wr8[j]; im[(8 * g + j) * 32 + c] = wi8[j];
    }
  }
  __syncthreads();

  float vr[4][4], vi[4][4];
#pragma unroll
  for (int q = 0; q < 4; ++q)
#pragma unroll
    for (int m = 0; m < 4; ++m) {
      const int pos = p + 8 * m + 32 * q;
      vr[q][m] = re[pos * 32 + c]; vi[q][m] = im[pos * 32 + c];
    }
#pragma unroll
  for (int q = 0; q < 4; ++q)
    ibf4r(vr[q][0], vi[q][0], vr[q][1], vi[q][1], vr[q][2], vi[q][2], vr[q][3], vi[q][3],
          twr[4 * p], twi[4 * p], twr[8 * p], twi[8 * p], twr[12 * p], twi[12 * p]);
#pragma unroll
  for (int m = 0; m < 4; ++m) {
    const int np = p + 8 * m;
    ibf4r(vr[0][m], vi[0][m], vr[1][m], vi[1][m], vr[2][m], vi[2][m], vr[3][m], vi[3][m],
          twr[np], twi[np], twr[2 * np], twi[2 * np], twr[3 * np], twi[3 * np]);
  }
#pragma unroll
  for (int q = 0; q < 4; ++q)
#pragma unroll
    for (int m = 0; m < 4; ++m)
      fp[(size_t)(p + 8 * m + 32 * q) * hs + c] = pk(vr[q][m], vi[q][m]);
}

// ---------------------------------------------------------------------------
// K3: inverse rFFT over W with frequency-domain skip: Z = Y*sc + X.
// Y from fq2, X from fq (unscaled). Direct nt store. grid (512, 12).
// ---------------------------------------------------------------------------
__global__ __launch_bounds__(TPB) void k_inv_w(const unsigned* __restrict__ fq2,
                                               const unsigned* __restrict__ fq,
                                               float* __restrict__ out) {
  __shared__ float re[4096], im[4096], twr[128], twi[128];
  const int t = threadIdx.x;
  const int bh = blockIdx.x;
  const int d0 = blockIdx.y << 6;
  TW_INIT();
  const int c = t & 31, p = t >> 5;
  const float sc = 0.0078125f;  // 1/128 (on Y only; X enters unscaled)

#pragma unroll
  for (int it = 0; it < 9; ++it) {
    const int idx = it * TPB + t;
    if (idx < FW * 32) {
      const int q = idx >> 5, cc = idx & 31;
      const size_t off = (size_t)(bh * FW + q) * 768 + d0 + 2 * cc;
      const uint2 vv = *(const uint2*)(fq2 + off);
      const uint2 xx = *(const uint2*)(fq + off);
      const float2 e = upk(vv.x), o = upk(vv.y);
      const float2 e2 = upk(xx.x), o2 = upk(xx.y);
      const float zer = e.x * sc + e2.x, zei = e.y * sc + e2.y;
      const float zor = o.x * sc + o2.x, zoi = o.y * sc + o2.y;
      re[q * 32 + cc] = zer - zoi; im[q * 32 + cc] = zei + zor;
      if (q >= 1 && q <= 63) {
        re[(128 - q) * 32 + cc] = zer + zoi;
        im[(128 - q) * 32 + cc] = zor - zei;
      }
    }
  }
  __syncthreads();

  float vr[4][4], vi[4][4];
#pragma unroll
  for (int q = 0; q < 4; ++q)
#pragma unroll
    for (int m = 0; m < 4; ++m) {
      const int pos = p + 8 * m + 32 * q;
      vr[q][m] = re[pos * 32 + c]; vi[q][m] = im[pos * 32 + c];
    }
#pragma unroll
  for (int m = 0; m < 4; ++m) {
    const int np = p + 8 * m;
    bf4reg<false>(vr[0][m], vi[0][m], vr[1][m], vi[1][m], vr[2][m], vi[2][m], vr[3][m], vi[3][m],
                  twr[np], -twi[np], twr[2 * np], -twi[2 * np], twr[3 * np], -twi[3 * np]);
  }
#pragma unroll
  for (int q = 0; q < 4; ++q)
    bf4reg<false>(vr[q][0], vi[q][0], vr[q][1], vi[q][1], vr[q][2], vi[q][2], vr[q][3], vi[q][3],
                  twr[4 * p], -twi[4 * p], twr[8 * p], -twi[8 * p], twr[12 * p], -twi[12 * p]);
#pragma unroll
  for (int q = 0; q < 4; ++q)
#pragma unroll
    for (int m = 0; m < 4; ++m) {
      const int pos = p + 8 * m + 32 * q;
      re[pos * 32 + c] = vr[q][m]; im[pos * 32 + c] = vi[q][m];
    }
  __syncthreads();

  f32x2* ov = (f32x2*)out;
#pragma unroll
  for (int half = 0; half < 2; ++half) {
    const int g = 8 * half + p;
    float wr8[8], wi8[8];
#pragma unroll
    for (int j = 0; j < 8; ++j) { wr8[j] = re[(8 * g + j) * 32 + c]; wi8[j] = im[(8 * g + j) * 32 + c]; }
    bf4reg<false>(wr8[0], wi8[0], wr8[2], wi8[2], wr8[4], wi8[4], wr8[6], wi8[6],
                  1.f, 0.f, 1.f, 0.f, 1.f, 0.f);
    bf4reg<false>(wr8[1], wi8[1], wr8[3], wi8[3], wr8[5], wi8[5], wr8[7], wi8[7],
                  twr[16], -twi[16], twr[32], -twi[32], twr[48], -twi[48]);
#pragma unroll
    for (int j = 0; j < 8; j += 2) {
      const float ar = wr8[j], ai = wi8[j], br = wr8[j + 1], bi = wi8[j + 1];
      wr8[j] = ar + br; wi8[j] = ai + bi;
      wr8[j + 1] = ar - br; wi8[j + 1] = ai - bi;
    }
#pragma unroll
    for (int j = 0; j < 8; ++j) {
      const int w = drevinv(8 * g + j);
      const size_t fi = (size_t)bh * 49152 + w * 384 + (d0 >> 1) + c;
      f32x2 o; o.x = wr8[j]; o.y = wi8[j];
      __builtin_nontemporal_store(o, &ov[fi]);
    }
  }
}

// ---------------------------------------------------------------------------
extern "C" void kernel_launch(void* const* d_in, const int* in_sizes, int n_in,
                              void* d_out, int out_size, void* d_ws, size_t ws_size,
                              hipStream_t stream) {
  const float* x   = (const float*)d_in[0];
  const float* w1r = (const float*)d_in[1];
  const float* w1i = (const float*)d_in[2];
  const float* b1  = (const float*)d_in[3];
  const float* w2r = (const float*)d_in[4];
  const float* w2i = (const float*)d_in[5];
  const float* b2  = (const float*)d_in[6];
  unsigned* fq  = (unsigned*)d_ws;                // X checkpoint
  unsigned* fq2 = fq + (size_t)BH_ * FW * 768;    // pipeline buffer
  float* out = (float*)d_out;

  const size_t need = (size_t)BH_ * FW * 768 * 4 * 2;  // 204,472,320 B
  if (ws_size < need) {
    fprintf(stderr, "kernel_launch: ws too small (%zu < %zu)\n", ws_size, need);
    return;
  }

  // packed bf16 weights at start of d_out (fully overwritten by k_inv_w later)
  unsigned short* wp = (unsigned short*)d_out;

  k_wpack<<<dim3(288), TPB, 0, stream>>>(w1r, w1i, w2r, w2i, wp);
  k_fwd_w<<<dim3(BH_, 12), TPB, 0, stream>>>(x, fq);
  k_fwd_h<<<dim3(B_, FW, 24), TPB, 0, stream>>>(fq, fq2);
  k_mlp_mfma<<<dim3(4160), TPB, 0, stream>>>(fq2, (const bf16x8*)wp, b1, b2);
  k_inv_h<<<dim3(B_, FW, 24), TPB, 0, stream>>>(fq2);
  k_inv_w<<<dim3(BH_, 12), TPB, 0, stream>>>(fq2, fq, out);
}